// Round 1
// baseline (789.418 us; speedup 1.0000x reference)
//
#include <hip/hip_runtime.h>

#define CC 96
#define C3 288
#define HH 256
#define WW 256
#define HWC 65536
#define NHEADS 8
#define W2 32

// K1: qkv = conv1x1(x) + bias. grid (HW/128, 3, bc), block 256.
// Tile: 128 pixels x 96 outputs, thread = (pt 0..15, ot 0..15), TM=8, TN=6.
__global__ __launch_bounds__(256) void k1_qkv(
    const float* __restrict__ x, const float* __restrict__ qw,
    const float* __restrict__ qb, float* __restrict__ pre, int b0)
{
  __shared__ float xs[32 * 128];
  __shared__ float wsm[32 * 96];
  const int t = threadIdx.x;
  const int p0 = blockIdx.x * 128;
  const int o0 = blockIdx.y * 96;
  const float* xb = x + (size_t)(b0 + blockIdx.z) * CC * HWC;
  float* preb = pre + (size_t)blockIdx.z * C3 * HWC;
  const int pt = t & 15;
  const int ot = t >> 4;

  float acc[8][6];
#pragma unroll
  for (int i = 0; i < 8; ++i)
#pragma unroll
    for (int j = 0; j < 6; ++j) acc[i][j] = 0.f;

  for (int c0 = 0; c0 < CC; c0 += 32) {
    __syncthreads();
#pragma unroll
    for (int r = 0; r < 4; ++r) {            // x chunk: 32c x 128p
      int f = r * 256 + t;
      int ci = f >> 5, cg = f & 31;
      float4 v = *reinterpret_cast<const float4*>(
          xb + (size_t)(c0 + ci) * HWC + p0 + cg * 4);
      *reinterpret_cast<float4*>(&xs[ci * 128 + cg * 4]) = v;
    }
#pragma unroll
    for (int r = 0; r < 12; ++r) {           // w chunk: 32c x 96o (transposed)
      int lin = r * 256 + t;
      int ci = lin / 96, oo = lin - ci * 96;
      wsm[ci * 96 + oo] = qw[(size_t)(o0 + oo) * 96 + c0 + ci];
    }
    __syncthreads();
#pragma unroll 2
    for (int ci = 0; ci < 32; ++ci) {
      float4 xv0 = *reinterpret_cast<const float4*>(&xs[ci * 128 + pt * 8]);
      float4 xv1 = *reinterpret_cast<const float4*>(&xs[ci * 128 + pt * 8 + 4]);
      const float* wp = &wsm[ci * 96 + ot * 6];
      float wv[6];
#pragma unroll
      for (int j = 0; j < 6; ++j) wv[j] = wp[j];
      float xv[8] = {xv0.x, xv0.y, xv0.z, xv0.w, xv1.x, xv1.y, xv1.z, xv1.w};
#pragma unroll
      for (int i = 0; i < 8; ++i)
#pragma unroll
        for (int j = 0; j < 6; ++j) acc[i][j] = fmaf(xv[i], wv[j], acc[i][j]);
    }
  }
#pragma unroll
  for (int j = 0; j < 6; ++j) {
    int o = o0 + ot * 6 + j;
    float bv = qb[o];
    float4 s0 = make_float4(acc[0][j] + bv, acc[1][j] + bv, acc[2][j] + bv, acc[3][j] + bv);
    float4 s1 = make_float4(acc[4][j] + bv, acc[5][j] + bv, acc[6][j] + bv, acc[7][j] + bv);
    float* op = preb + (size_t)o * HWC + p0 + pt * 8;
    *reinterpret_cast<float4*>(op) = s0;
    *reinterpret_cast<float4*>(op + 4) = s1;
  }
}

// K2: depthwise 3x3 + bias. grid (288, 32, bc), block 256 (one row width).
__global__ __launch_bounds__(256) void k2_dw(
    const float* __restrict__ pre, const float* __restrict__ dww,
    const float* __restrict__ dwb, float* __restrict__ dwo)
{
  __shared__ float s[10 * 264];
  const int t = threadIdx.x;
  const int c3 = blockIdx.x;
  const int h0 = blockIdx.y * 8;
  const float* in = pre + ((size_t)blockIdx.z * C3 + c3) * HWC;
  float* out = dwo + ((size_t)blockIdx.z * C3 + c3) * HWC;
#pragma unroll
  for (int r = 0; r < 10; ++r) {
    int hh = h0 - 1 + r;
    float v = (hh >= 0 && hh < HH) ? in[hh * WW + t] : 0.f;
    s[r * 264 + 1 + t] = v;
  }
  if (t < 10) { s[t * 264] = 0.f; s[t * 264 + 257] = 0.f; }
  __syncthreads();
  float wg[9];
#pragma unroll
  for (int i = 0; i < 9; ++i) wg[i] = dww[c3 * 9 + i];
  const float bias = dwb[c3];
#pragma unroll
  for (int r = 0; r < 8; ++r) {
    float a = bias;
#pragma unroll
    for (int dy = 0; dy < 3; ++dy)
#pragma unroll
      for (int dx = 0; dx < 3; ++dx)
        a = fmaf(s[(r + dy) * 264 + t + dx], wg[dy * 3 + dx], a);
    out[(h0 + r) * WW + t] = a;
  }
}

// K3: partial Gram per (c, head, b): G_c[i][j] = sum_h q[c,h,i]*k[c,h,j];
// plus sumsq of q,k columns via atomics. grid (96, 8, bc), block 256.
__global__ __launch_bounds__(256) void k3_gram(
    const float* __restrict__ dwo, float* __restrict__ gpart, float* __restrict__ ssq)
{
  __shared__ float qs[256 * 32];
  __shared__ float ks[256 * 32];
  const int t = threadIdx.x;
  const int c = blockIdx.x, head = blockIdx.y, bz = blockIdx.z;
  const float* qp = dwo + ((size_t)bz * C3 + c) * HWC + head * W2;
  const float* kp = dwo + ((size_t)bz * C3 + CC + c) * HWC + head * W2;
#pragma unroll 4
  for (int it = 0; it < 32; ++it) {
    int lin = it * 256 + t;
    int h = lin >> 5, j = lin & 31;
    qs[lin] = qp[h * WW + j];
    ks[lin] = kp[h * WW + j];
  }
  __syncthreads();
  const int i = t & 31, jg = t >> 5;
  float a0 = 0, a1 = 0, a2 = 0, a3 = 0;
  for (int h = 0; h < 256; ++h) {
    float qv = qs[h * 32 + i];
    float4 kv = *reinterpret_cast<const float4*>(&ks[h * 32 + jg * 4]);
    a0 = fmaf(qv, kv.x, a0); a1 = fmaf(qv, kv.y, a1);
    a2 = fmaf(qv, kv.z, a2); a3 = fmaf(qv, kv.w, a3);
  }
  float* gp = gpart + (((size_t)bz * NHEADS + head) * CC + c) * 1024;
  gp[(jg * 4 + 0) * 32 + i] = a0;
  gp[(jg * 4 + 1) * 32 + i] = a1;
  gp[(jg * 4 + 2) * 32 + i] = a2;
  gp[(jg * 4 + 3) * 32 + i] = a3;
  if (t < 64) {
    const float* src = (t < 32) ? qs : ks;
    const int col = t & 31;
    float ssum = 0;
    for (int h = 0; h < 256; ++h) { float v = src[h * 32 + col]; ssum = fmaf(v, v, ssum); }
    atomicAdd(&ssq[((size_t)bz * 2 + (t >> 5)) * 256 + head * W2 + col], ssum);
  }
}

// K4: reduce Gram over c, normalize by norms, temperature, softmax rows.
// grid (8, bc), block 256.
__global__ __launch_bounds__(256) void k4_attn(
    const float* __restrict__ gpart, const float* __restrict__ ssq,
    const float* __restrict__ temp, float* __restrict__ attn)
{
  __shared__ float lg[1024];
  const int t = threadIdx.x;
  const int head = blockIdx.x, bz = blockIdx.y;
  const float* gp = gpart + ((size_t)bz * NHEADS + head) * CC * 1024;
  float a0 = 0, a1 = 0, a2 = 0, a3 = 0;
  for (int c = 0; c < CC; ++c) {
    const float* g = gp + c * 1024;
    a0 += g[t]; a1 += g[t + 256]; a2 += g[t + 512]; a3 += g[t + 768];
  }
  lg[t] = a0; lg[t + 256] = a1; lg[t + 512] = a2; lg[t + 768] = a3;
  __syncthreads();
  if (t < 32) {
    const int i = t;
    const float* sq_ = ssq + (size_t)bz * 2 * 256 + head * W2;
    const float* sk_ = ssq + ((size_t)bz * 2 + 1) * 256 + head * W2;
    float invq = 1.f / fmaxf(sqrtf(sq_[i]), 1e-12f);
    float tpq = temp[head] * invq;
    float row[32];
    float m = -1e30f;
#pragma unroll
    for (int j = 0; j < 32; ++j) {
      float invk = 1.f / fmaxf(sqrtf(sk_[j]), 1e-12f);
      float v = lg[j * 32 + i] * tpq * invk;   // G stored as [j*32+i]
      row[j] = v;
      m = fmaxf(m, v);
    }
    float ssum = 0;
#pragma unroll
    for (int j = 0; j < 32; ++j) { row[j] = expf(row[j] - m); ssum += row[j]; }
    float inv = 1.f / ssum;
    float* ap = attn + ((size_t)bz * NHEADS + head) * 1024 + i * 32;
#pragma unroll
    for (int j = 0; j < 32; ++j) ap[j] = row[j] * inv;
  }
}

// K5: out = proj( attn @ v ) + proj_b, fused. grid (8, 256, bc), block 256.
__global__ __launch_bounds__(256) void k5_out(
    const float* __restrict__ dwo, const float* __restrict__ attn,
    const float* __restrict__ pw, const float* __restrict__ pb,
    float* __restrict__ out, int b0)
{
  __shared__ float vt[32 * 96];    // phase1: v^T [j][c]; after sync reused as t[c][i]
  __shared__ float at[32 * 33];    // attn^T [j][i]
  __shared__ float pwt[96 * 96];   // proj_w^T [c][o]
  const int t = threadIdx.x;
  const int head = blockIdx.x, h = blockIdx.y, bz = blockIdx.z;
  const float* vsrc = dwo + ((size_t)bz * C3 + 2 * CC) * HWC + h * WW + head * W2;
#pragma unroll
  for (int r = 0; r < 12; ++r) {
    int lin = r * 256 + t;
    int c = lin >> 5, j = lin & 31;
    vt[j * 96 + c] = vsrc[(size_t)c * HWC + j];
  }
  {
    const float* ap = attn + ((size_t)bz * NHEADS + head) * 1024;
#pragma unroll
    for (int r = 0; r < 4; ++r) {
      int lin = r * 256 + t;
      int i = lin >> 5, j = lin & 31;
      at[j * 33 + i] = ap[lin];
    }
  }
#pragma unroll
  for (int r = 0; r < 36; ++r) {
    int lin = r * 256 + t;
    int o = lin / 96, c = lin - o * 96;
    pwt[c * 96 + o] = pw[lin];
  }
  __syncthreads();
  const int i = t & 31, cg = t >> 5;
  // phase1: t[c][i] = sum_j v[c][j] * attn[i][j]
  float acc[12];
#pragma unroll
  for (int cc = 0; cc < 12; ++cc) acc[cc] = 0.f;
  for (int j = 0; j < 32; ++j) {
    float av = at[j * 33 + i];
    const float* vp = &vt[j * 96 + cg * 12];
#pragma unroll
    for (int cc = 0; cc < 12; ++cc) acc[cc] = fmaf(vp[cc], av, acc[cc]);
  }
  __syncthreads();                 // everyone done reading vt
  float* tl = vt;                  // alias: tl[c*32 + i]
#pragma unroll
  for (int cc = 0; cc < 12; ++cc) tl[(cg * 12 + cc) * 32 + i] = acc[cc];
  __syncthreads();
  // phase2: out[o][i] = pb[o] + sum_c pw[o][c] * t[c][i]
  float oacc[12];
#pragma unroll
  for (int oo = 0; oo < 12; ++oo) oacc[oo] = pb[cg * 12 + oo];
  for (int c = 0; c < 96; ++c) {
    float tv = tl[c * 32 + i];
    const float* pp = &pwt[c * 96 + cg * 12];
#pragma unroll
    for (int oo = 0; oo < 12; ++oo) oacc[oo] = fmaf(pp[oo], tv, oacc[oo]);
  }
  float* ob = out + (size_t)(b0 + bz) * CC * HWC + h * WW + head * W2 + i;
#pragma unroll
  for (int oo = 0; oo < 12; ++oo) ob[(size_t)(cg * 12 + oo) * HWC] = oacc[oo];
}

extern "C" void kernel_launch(void* const* d_in, const int* in_sizes, int n_in,
                              void* d_out, int out_size, void* d_ws, size_t ws_size,
                              hipStream_t stream)
{
  const float* x      = (const float*)d_in[0];
  const float* qkv_w  = (const float*)d_in[1];
  const float* qkv_b  = (const float*)d_in[2];
  const float* dw_w   = (const float*)d_in[3];
  const float* dw_b   = (const float*)d_in[4];
  const float* proj_w = (const float*)d_in[5];
  const float* proj_b = (const float*)d_in[6];
  const float* temp   = (const float*)d_in[7];
  float* out = (float*)d_out;

  const size_t per_pre  = (size_t)C3 * HWC * 4;            // 75.5 MB
  const size_t per_gp   = (size_t)NHEADS * CC * 1024 * 4;  // 3.1 MB
  const size_t per_ssq  = (size_t)2 * 256 * 4;
  const size_t per_attn = (size_t)NHEADS * 1024 * 4;
  const size_t per_b = per_pre * 2 + per_gp + per_ssq + per_attn;

  int bc = 4;
  while (bc > 1 && per_b * (size_t)bc > ws_size) bc >>= 1;

  char* p = (char*)d_ws;
  float* pre   = (float*)p; p += per_pre * bc;
  float* dwo   = (float*)p; p += per_pre * bc;
  float* gpart = (float*)p; p += per_gp * bc;
  float* ssq   = (float*)p; p += per_ssq * bc;
  float* attn  = (float*)p; p += per_attn * bc;

  for (int b0 = 0; b0 < 4; b0 += bc) {
    k1_qkv<<<dim3(HWC / 128, 3, bc), 256, 0, stream>>>(x, qkv_w, qkv_b, pre, b0);
    k2_dw<<<dim3(C3, HH / 8, bc), 256, 0, stream>>>(pre, dw_w, dw_b, dwo);
    hipMemsetAsync(ssq, 0, per_ssq * bc, stream);
    k3_gram<<<dim3(CC, NHEADS, bc), 256, 0, stream>>>(dwo, gpart, ssq);
    k4_attn<<<dim3(NHEADS, bc), 256, 0, stream>>>(gpart, ssq, temp, attn);
    k5_out<<<dim3(NHEADS, HH, bc), 256, 0, stream>>>(dwo, attn, proj_w, proj_b, out, b0);
  }
}

// Round 2
// 559.609 us; speedup vs baseline: 1.4107x; 1.4107x over previous
//
#include <hip/hip_runtime.h>

#define CC 96
#define C3 288
#define HH 256
#define WW 256
#define HWC 65536
#define NHEADS 8
#define W2 32

__device__ __forceinline__ float bf2f(unsigned short u) {
  return __uint_as_float(((unsigned)u) << 16);
}
__device__ __forceinline__ unsigned short f2bf(float f) {
  unsigned u = __float_as_uint(f);
  unsigned r = u + 0x7fffu + ((u >> 16) & 1u);
  return (unsigned short)(r >> 16);
}

// K1: qkv = conv1x1(x) + bias. grid (512, 3, bc), block 256.
// blockIdx.y: 0,1 -> q,k (bf16 out), 2 -> v (fp32 out).
// Thread tile: 8 px (two groups of 4, stride-4 lanes -> 2-way LDS = free) x 6 out-ch.
__global__ __launch_bounds__(256) void k1_qkv(
    const float* __restrict__ x, const float* __restrict__ qw,
    const float* __restrict__ qb, unsigned short* __restrict__ pre_qk,
    float* __restrict__ pre_v, int b0)
{
  __shared__ float xs[32 * 128];
  __shared__ float wsm[32 * 96];
  const int t = threadIdx.x;
  const int p0 = blockIdx.x * 128;
  const int grp = blockIdx.y;
  const int o0 = grp * 96;
  const int bz = blockIdx.z;
  const float* xb = x + (size_t)(b0 + bz) * CC * HWC;
  const int pt = t & 15;
  const int ot = t >> 4;

  float acc[8][6];
#pragma unroll
  for (int i = 0; i < 8; ++i)
#pragma unroll
    for (int j = 0; j < 6; ++j) acc[i][j] = 0.f;

  for (int c0 = 0; c0 < CC; c0 += 32) {
    __syncthreads();
#pragma unroll
    for (int r = 0; r < 4; ++r) {
      int f = r * 256 + t;
      int ci = f >> 5, cg = f & 31;
      float4 v = *reinterpret_cast<const float4*>(
          xb + (size_t)(c0 + ci) * HWC + p0 + cg * 4);
      *reinterpret_cast<float4*>(&xs[ci * 128 + cg * 4]) = v;
    }
#pragma unroll
    for (int r = 0; r < 12; ++r) {
      int lin = r * 256 + t;
      int ci = lin / 96, oo = lin - ci * 96;
      wsm[ci * 96 + oo] = qw[(size_t)(o0 + oo) * 96 + c0 + ci];
    }
    __syncthreads();
#pragma unroll 2
    for (int ci = 0; ci < 32; ++ci) {
      float4 xv0 = *reinterpret_cast<const float4*>(&xs[ci * 128 + pt * 4]);
      float4 xv1 = *reinterpret_cast<const float4*>(&xs[ci * 128 + 64 + pt * 4]);
      const float* wp = &wsm[ci * 96 + ot * 6];
      float2 wv0 = *reinterpret_cast<const float2*>(wp);
      float2 wv1 = *reinterpret_cast<const float2*>(wp + 2);
      float2 wv2 = *reinterpret_cast<const float2*>(wp + 4);
      float wv[6] = {wv0.x, wv0.y, wv1.x, wv1.y, wv2.x, wv2.y};
      float xv[8] = {xv0.x, xv0.y, xv0.z, xv0.w, xv1.x, xv1.y, xv1.z, xv1.w};
#pragma unroll
      for (int i = 0; i < 8; ++i)
#pragma unroll
        for (int j = 0; j < 6; ++j) acc[i][j] = fmaf(xv[i], wv[j], acc[i][j]);
    }
  }
#pragma unroll
  for (int j = 0; j < 6; ++j) {
    int o = ot * 6 + j;                 // channel within 96-group
    float bv = qb[o0 + o];
    float4 a = make_float4(acc[0][j] + bv, acc[1][j] + bv, acc[2][j] + bv, acc[3][j] + bv);
    float4 b = make_float4(acc[4][j] + bv, acc[5][j] + bv, acc[6][j] + bv, acc[7][j] + bv);
    if (grp < 2) {
      unsigned short* op = pre_qk + ((size_t)bz * 192 + o0 + o) * HWC + p0 + pt * 4;
      ushort4 u0, u1;
      u0.x = f2bf(a.x); u0.y = f2bf(a.y); u0.z = f2bf(a.z); u0.w = f2bf(a.w);
      u1.x = f2bf(b.x); u1.y = f2bf(b.y); u1.z = f2bf(b.z); u1.w = f2bf(b.w);
      *reinterpret_cast<ushort4*>(op) = u0;
      *reinterpret_cast<ushort4*>(op + 64) = u1;
    } else {
      float* op = pre_v + ((size_t)bz * 96 + o) * HWC + p0 + pt * 4;
      *reinterpret_cast<float4*>(op) = a;
      *reinterpret_cast<float4*>(op + 64) = b;
    }
  }
}

// K2: depthwise 3x3 + bias. Tile 32 rows x 256 cols, vectorized x4.
// BF=1: bf16 in/out (192 ch), BF=0: fp32 in/out (96 ch). grid (nch, 8, bc).
template <int BF>
__global__ __launch_bounds__(256) void k2_dw(
    const void* __restrict__ pre, const float* __restrict__ dww,
    const float* __restrict__ dwb, void* __restrict__ dwo, int cbase)
{
  __shared__ float s[34 * 268];
  const int t = threadIdx.x;
  const int c3 = blockIdx.x;
  const int h0 = blockIdx.y * 32;
  const int bz = blockIdx.z;
  const int nch = BF ? 192 : 96;
  const size_t choff = ((size_t)bz * nch + c3) * HWC;
  const int rt = t >> 6, col4 = (t & 63) * 4;

#pragma unroll
  for (int r = 0; r < 9; ++r) {
    int row = r * 4 + rt;
    if (row < 34) {
      int hh = h0 + row - 1;
      float4 v = make_float4(0.f, 0.f, 0.f, 0.f);
      if (hh >= 0 && hh < HH) {
        if (BF) {
          ushort4 u = *reinterpret_cast<const ushort4*>(
              (const unsigned short*)pre + choff + hh * WW + col4);
          v = make_float4(bf2f(u.x), bf2f(u.y), bf2f(u.z), bf2f(u.w));
        } else {
          v = *reinterpret_cast<const float4*>((const float*)pre + choff + hh * WW + col4);
        }
      }
      *reinterpret_cast<float4*>(&s[row * 268 + 4 + col4]) = v;
    }
  }
  if (t < 34) { s[t * 268 + 3] = 0.f; s[t * 268 + 260] = 0.f; }
  __syncthreads();

  float wg[9];
#pragma unroll
  for (int i = 0; i < 9; ++i) wg[i] = dww[(cbase + c3) * 9 + i];
  const float bias = dwb[cbase + c3];

#pragma unroll
  for (int rr = 0; rr < 8; ++rr) {
    int orow = rr * 4 + rt;
    float a0 = bias, a1 = bias, a2 = bias, a3 = bias;
#pragma unroll
    for (int dy = 0; dy < 3; ++dy) {
      const float* rowp = &s[(orow + dy) * 268 + 4 + col4];
      float4 rA = *reinterpret_cast<const float4*>(rowp - 4);
      float4 rB = *reinterpret_cast<const float4*>(rowp);
      float4 rC = *reinterpret_cast<const float4*>(rowp + 4);
      float w0 = wg[dy * 3 + 0], w1 = wg[dy * 3 + 1], w2 = wg[dy * 3 + 2];
      a0 = fmaf(rA.w, w0, fmaf(rB.x, w1, fmaf(rB.y, w2, a0)));
      a1 = fmaf(rB.x, w0, fmaf(rB.y, w1, fmaf(rB.z, w2, a1)));
      a2 = fmaf(rB.y, w0, fmaf(rB.z, w1, fmaf(rB.w, w2, a2)));
      a3 = fmaf(rB.z, w0, fmaf(rB.w, w1, fmaf(rC.x, w2, a3)));
    }
    if (BF) {
      ushort4 u;
      u.x = f2bf(a0); u.y = f2bf(a1); u.z = f2bf(a2); u.w = f2bf(a3);
      *reinterpret_cast<ushort4*>((unsigned short*)dwo + choff + (h0 + orow) * WW + col4) = u;
    } else {
      *reinterpret_cast<float4*>((float*)dwo + choff + (h0 + orow) * WW + col4) =
          make_float4(a0, a1, a2, a3);
    }
  }
}

// K3: partial Gram per (c, head, b) from bf16 q,k; + sumsq via atomics.
__global__ __launch_bounds__(256) void k3_gram(
    const unsigned short* __restrict__ dwo_qk, float* __restrict__ gpart,
    float* __restrict__ ssq)
{
  __shared__ float qs[256 * 32];
  __shared__ float ks[256 * 32];
  const int t = threadIdx.x;
  const int c = blockIdx.x, head = blockIdx.y, bz = blockIdx.z;
  const unsigned short* qp = dwo_qk + ((size_t)bz * 192 + c) * HWC + head * W2;
  const unsigned short* kp = dwo_qk + ((size_t)bz * 192 + 96 + c) * HWC + head * W2;
#pragma unroll
  for (int it = 0; it < 8; ++it) {
    int lin = it * 256 + t;
    int h = lin >> 3, j4 = (lin & 7) * 4;
    ushort4 qu = *reinterpret_cast<const ushort4*>(qp + h * WW + j4);
    ushort4 ku = *reinterpret_cast<const ushort4*>(kp + h * WW + j4);
    *reinterpret_cast<float4*>(&qs[h * 32 + j4]) =
        make_float4(bf2f(qu.x), bf2f(qu.y), bf2f(qu.z), bf2f(qu.w));
    *reinterpret_cast<float4*>(&ks[h * 32 + j4]) =
        make_float4(bf2f(ku.x), bf2f(ku.y), bf2f(ku.z), bf2f(ku.w));
  }
  __syncthreads();
  const int i = t & 31, jg = t >> 5;
  float a0 = 0, a1 = 0, a2 = 0, a3 = 0;
  for (int h = 0; h < 256; ++h) {
    float qv = qs[h * 32 + i];
    float4 kv = *reinterpret_cast<const float4*>(&ks[h * 32 + jg * 4]);
    a0 = fmaf(qv, kv.x, a0); a1 = fmaf(qv, kv.y, a1);
    a2 = fmaf(qv, kv.z, a2); a3 = fmaf(qv, kv.w, a3);
  }
  float* gp = gpart + (((size_t)bz * NHEADS + head) * CC + c) * 1024;
  gp[(jg * 4 + 0) * 32 + i] = a0;
  gp[(jg * 4 + 1) * 32 + i] = a1;
  gp[(jg * 4 + 2) * 32 + i] = a2;
  gp[(jg * 4 + 3) * 32 + i] = a3;
  if (t < 64) {
    const float* src = (t < 32) ? qs : ks;
    const int col = t & 31;
    float ssum = 0;
    for (int h = 0; h < 256; ++h) { float v = src[h * 32 + col]; ssum = fmaf(v, v, ssum); }
    atomicAdd(&ssq[((size_t)bz * 2 + (t >> 5)) * 256 + head * W2 + col], ssum);
  }
}

// K4: reduce Gram over c, normalize, temperature, softmax. grid (8, bc).
__global__ __launch_bounds__(256) void k4_attn(
    const float* __restrict__ gpart, const float* __restrict__ ssq,
    const float* __restrict__ temp, float* __restrict__ attn)
{
  __shared__ float lg[1024];
  const int t = threadIdx.x;
  const int head = blockIdx.x, bz = blockIdx.y;
  const float* gp = gpart + ((size_t)bz * NHEADS + head) * CC * 1024;
  float a0 = 0, a1 = 0, a2 = 0, a3 = 0;
  for (int c = 0; c < CC; ++c) {
    const float* g = gp + c * 1024;
    a0 += g[t]; a1 += g[t + 256]; a2 += g[t + 512]; a3 += g[t + 768];
  }
  lg[t] = a0; lg[t + 256] = a1; lg[t + 512] = a2; lg[t + 768] = a3;
  __syncthreads();
  if (t < 32) {
    const int i = t;
    const float* sq_ = ssq + (size_t)bz * 2 * 256 + head * W2;
    const float* sk_ = ssq + ((size_t)bz * 2 + 1) * 256 + head * W2;
    float invq = 1.f / fmaxf(sqrtf(sq_[i]), 1e-12f);
    float tpq = temp[head] * invq;
    float row[32];
    float m = -1e30f;
#pragma unroll
    for (int j = 0; j < 32; ++j) {
      float invk = 1.f / fmaxf(sqrtf(sk_[j]), 1e-12f);
      float v = lg[j * 32 + i] * tpq * invk;
      row[j] = v;
      m = fmaxf(m, v);
    }
    float ssum = 0;
#pragma unroll
    for (int j = 0; j < 32; ++j) { row[j] = expf(row[j] - m); ssum += row[j]; }
    float inv = 1.f / ssum;
    float* ap = attn + ((size_t)bz * NHEADS + head) * 1024 + i * 32;
#pragma unroll
    for (int j = 0; j < 32; ++j) ap[j] = row[j] * inv;
  }
}

// K5: out = proj(attn @ v) + proj_b. grid (8, 64, bc), 4 h-rows per block.
// Conflict-free LDS: vs[c][32] linear, tl[c][32], pwt[c][100] padded for b128.
__global__ __launch_bounds__(256) void k5_out(
    const float* __restrict__ dwo_v, const float* __restrict__ attn,
    const float* __restrict__ pw, const float* __restrict__ pb,
    float* __restrict__ out, int b0)
{
  __shared__ float pwt[96 * 100];
  __shared__ float vs[96 * 32];
  __shared__ float tl[96 * 32];
  const int t = threadIdx.x;
  const int head = blockIdx.x, hb = blockIdx.y, bz = blockIdx.z;
  const int i = t & 31, cg = t >> 5;

#pragma unroll
  for (int r = 0; r < 36; ++r) {
    int lin = r * 256 + t;
    int o = lin / 96, c = lin - o * 96;
    pwt[c * 100 + o] = pw[lin];
  }
  float atr[32];
  {
    const float* ap = attn + ((size_t)bz * NHEADS + head) * 1024 + i * 32;
#pragma unroll
    for (int j4 = 0; j4 < 8; ++j4) {
      float4 a = *reinterpret_cast<const float4*>(ap + j4 * 4);
      atr[j4 * 4 + 0] = a.x; atr[j4 * 4 + 1] = a.y;
      atr[j4 * 4 + 2] = a.z; atr[j4 * 4 + 3] = a.w;
    }
  }
  float pbr[12];
#pragma unroll
  for (int oo = 0; oo < 12; ++oo) pbr[oo] = pb[cg * 12 + oo];
  const float* vbase = dwo_v + (size_t)bz * 96 * HWC + head * W2;
  __syncthreads();

  for (int r = 0; r < 4; ++r) {
    if (r) __syncthreads();
    const int h = hb * 4 + r;
#pragma unroll
    for (int it = 0; it < 3; ++it) {
      int lin = it * 256 + t;
      int c = lin >> 3, j4 = (lin & 7) * 4;
      *reinterpret_cast<float4*>(&vs[c * 32 + j4]) =
          *reinterpret_cast<const float4*>(vbase + (size_t)c * HWC + h * WW + j4);
    }
    __syncthreads();
    float acc[12];
#pragma unroll
    for (int cc = 0; cc < 12; ++cc) {
      const float* vp = &vs[(cg * 12 + cc) * 32];
      float a = 0.f;
#pragma unroll
      for (int j4 = 0; j4 < 8; ++j4) {
        float4 vv = *reinterpret_cast<const float4*>(vp + j4 * 4);
        a = fmaf(vv.x, atr[j4 * 4 + 0], a);
        a = fmaf(vv.y, atr[j4 * 4 + 1], a);
        a = fmaf(vv.z, atr[j4 * 4 + 2], a);
        a = fmaf(vv.w, atr[j4 * 4 + 3], a);
      }
      acc[cc] = a;
    }
#pragma unroll
    for (int cc = 0; cc < 12; ++cc) tl[(cg * 12 + cc) * 32 + i] = acc[cc];
    __syncthreads();
    float oacc[12];
#pragma unroll
    for (int oo = 0; oo < 12; ++oo) oacc[oo] = pbr[oo];
    for (int c = 0; c < 96; ++c) {
      float tv = tl[c * 32 + i];
      const float* pp = &pwt[c * 100 + cg * 12];
      float4 w0 = *reinterpret_cast<const float4*>(pp);
      float4 w1 = *reinterpret_cast<const float4*>(pp + 4);
      float4 w2 = *reinterpret_cast<const float4*>(pp + 8);
      oacc[0] = fmaf(w0.x, tv, oacc[0]);  oacc[1] = fmaf(w0.y, tv, oacc[1]);
      oacc[2] = fmaf(w0.z, tv, oacc[2]);  oacc[3] = fmaf(w0.w, tv, oacc[3]);
      oacc[4] = fmaf(w1.x, tv, oacc[4]);  oacc[5] = fmaf(w1.y, tv, oacc[5]);
      oacc[6] = fmaf(w1.z, tv, oacc[6]);  oacc[7] = fmaf(w1.w, tv, oacc[7]);
      oacc[8] = fmaf(w2.x, tv, oacc[8]);  oacc[9] = fmaf(w2.y, tv, oacc[9]);
      oacc[10] = fmaf(w2.z, tv, oacc[10]); oacc[11] = fmaf(w2.w, tv, oacc[11]);
    }
    float* ob = out + ((size_t)(b0 + bz) * CC + cg * 12) * HWC + h * WW + head * W2 + i;
#pragma unroll
    for (int oo = 0; oo < 12; ++oo) ob[(size_t)oo * HWC] = oacc[oo];
  }
}

extern "C" void kernel_launch(void* const* d_in, const int* in_sizes, int n_in,
                              void* d_out, int out_size, void* d_ws, size_t ws_size,
                              hipStream_t stream)
{
  const float* x      = (const float*)d_in[0];
  const float* qkv_w  = (const float*)d_in[1];
  const float* qkv_b  = (const float*)d_in[2];
  const float* dw_w   = (const float*)d_in[3];
  const float* dw_b   = (const float*)d_in[4];
  const float* proj_w = (const float*)d_in[5];
  const float* proj_b = (const float*)d_in[6];
  const float* temp   = (const float*)d_in[7];
  float* out = (float*)d_out;

  const size_t per_preqk = (size_t)192 * HWC * 2;
  const size_t per_prev  = (size_t)96 * HWC * 4;
  const size_t per_gp    = (size_t)NHEADS * CC * 1024 * 4;
  const size_t per_ssq   = (size_t)2 * 256 * 4;
  const size_t per_attn  = (size_t)NHEADS * 1024 * 4;
  const size_t per_b = per_preqk * 2 + per_prev * 2 + per_gp + per_ssq + per_attn;

  int bc = 4;
  while (bc > 1 && per_b * (size_t)bc > ws_size) bc >>= 1;

  char* p = (char*)d_ws;
  unsigned short* pre_qk = (unsigned short*)p; p += per_preqk * bc;
  float*          pre_v  = (float*)p;          p += per_prev * bc;
  unsigned short* dwo_qk = (unsigned short*)p; p += per_preqk * bc;
  float*          dwo_v  = (float*)p;          p += per_prev * bc;
  float* gpart = (float*)p; p += per_gp * bc;
  float* ssq   = (float*)p; p += per_ssq * bc;
  float* attn  = (float*)p; p += per_attn * bc;

  for (int b0 = 0; b0 < 4; b0 += bc) {
    k1_qkv<<<dim3(512, 3, bc), 256, 0, stream>>>(x, qkv_w, qkv_b, pre_qk, pre_v, b0);
    k2_dw<1><<<dim3(192, 8, bc), 256, 0, stream>>>(pre_qk, dw_w, dw_b, dwo_qk, 0);
    k2_dw<0><<<dim3(96, 8, bc), 256, 0, stream>>>(pre_v, dw_w, dw_b, dwo_v, 192);
    hipMemsetAsync(ssq, 0, per_ssq * bc, stream);
    k3_gram<<<dim3(CC, NHEADS, bc), 256, 0, stream>>>(dwo_qk, gpart, ssq);
    k4_attn<<<dim3(NHEADS, bc), 256, 0, stream>>>(gpart, ssq, temp, attn);
    k5_out<<<dim3(NHEADS, 64, bc), 256, 0, stream>>>(dwo_v, attn, proj_w, proj_b, out, b0);
  }
}

// Round 3
// 408.223 us; speedup vs baseline: 1.9338x; 1.3708x over previous
//
#include <hip/hip_runtime.h>

#define CC 96
#define C3 288
#define HH 256
#define WW 256
#define HWC 65536
#define NHEADS 8
#define W2 32

typedef __bf16 bf16x8 __attribute__((ext_vector_type(8)));
typedef float f32x4 __attribute__((ext_vector_type(4)));

__device__ __forceinline__ float bf2f(unsigned short u) {
  return __uint_as_float(((unsigned)u) << 16);
}
__device__ __forceinline__ unsigned short f2bf(float f) {
  unsigned u = __float_as_uint(f);
  unsigned r = u + 0x7fffu + ((u >> 16) & 1u);
  return (unsigned short)(r >> 16);
}

// K1: qkv conv1x1 via bf16 MFMA. grid (512, 3, bc), block 256 (4 waves).
// Block tile: 128 px x 96 oc, K=96 whole. Wave tile: 64 px x 48 oc.
// A = x (M=px, K=ic) staged [px][ic] pad 104; B = W staged [oc][ic] pad 104.
__global__ __launch_bounds__(256) void k1_qkv_mfma(
    const float* __restrict__ x, const float* __restrict__ qw,
    const float* __restrict__ qb, unsigned short* __restrict__ pre, int b0)
{
  __shared__ __align__(16) unsigned short As[128 * 104];
  __shared__ __align__(16) unsigned short Ws[96 * 104];
  const int t = threadIdx.x;
  const int p0 = blockIdx.x * 128;
  const int o0 = blockIdx.y * 96;
  const int bz = blockIdx.z;
  const float* xb = x + (size_t)(b0 + bz) * CC * HWC;

  // Stage A: 48 ic-pairs x 32 px4-groups; transpose via packed b32 writes.
#pragma unroll
  for (int r = 0; r < 6; ++r) {
    int lin = r * 256 + t;
    int icp = lin >> 5;            // 0..47
    int p4 = (lin & 31) * 4;       // 0..124
    float4 v0 = *reinterpret_cast<const float4*>(xb + (size_t)(2 * icp) * HWC + p0 + p4);
    float4 v1 = *reinterpret_cast<const float4*>(xb + (size_t)(2 * icp + 1) * HWC + p0 + p4);
    float a0[4] = {v0.x, v0.y, v0.z, v0.w};
    float a1[4] = {v1.x, v1.y, v1.z, v1.w};
#pragma unroll
    for (int j = 0; j < 4; ++j) {
      unsigned pk = (unsigned)f2bf(a0[j]) | ((unsigned)f2bf(a1[j]) << 16);
      *reinterpret_cast<unsigned*>(&As[(p4 + j) * 104 + 2 * icp]) = pk;
    }
  }
  // Stage W: 96 oc x 96 ic, already [oc][ic] in memory.
#pragma unroll
  for (int r = 0; r < 9; ++r) {
    int lin = r * 256 + t;         // 0..2303
    int oc = lin / 24;
    int ic4 = (lin - oc * 24) * 4;
    float4 w = *reinterpret_cast<const float4*>(qw + (size_t)(o0 + oc) * 96 + ic4);
    ushort4 u;
    u.x = f2bf(w.x); u.y = f2bf(w.y); u.z = f2bf(w.z); u.w = f2bf(w.w);
    *reinterpret_cast<ushort4*>(&Ws[oc * 104 + ic4]) = u;
  }
  __syncthreads();

  const int wave = t >> 6, lane = t & 63;
  const int wm = wave & 1, wn = wave >> 1;   // px-half, oc-half
  const int row = lane & 15, kg = lane >> 4;

  f32x4 acc[4][3];
#pragma unroll
  for (int mt = 0; mt < 4; ++mt)
#pragma unroll
    for (int nt = 0; nt < 3; ++nt) acc[mt][nt] = (f32x4){0.f, 0.f, 0.f, 0.f};

#pragma unroll
  for (int kk = 0; kk < 3; ++kk) {
    bf16x8 a[4], b[3];
#pragma unroll
    for (int mt = 0; mt < 4; ++mt)
      a[mt] = *reinterpret_cast<const bf16x8*>(
          &As[(wm * 64 + mt * 16 + row) * 104 + kk * 32 + kg * 8]);
#pragma unroll
    for (int nt = 0; nt < 3; ++nt)
      b[nt] = *reinterpret_cast<const bf16x8*>(
          &Ws[(wn * 48 + nt * 16 + row) * 104 + kk * 32 + kg * 8]);
#pragma unroll
    for (int mt = 0; mt < 4; ++mt)
#pragma unroll
      for (int nt = 0; nt < 3; ++nt)
        acc[mt][nt] = __builtin_amdgcn_mfma_f32_16x16x32_bf16(
            a[mt], b[nt], acc[mt][nt], 0, 0, 0);
  }

  // Epilogue: bias + bf16 store. D: n=lane&15, m=(lane>>4)*4+reg (px-consecutive).
#pragma unroll
  for (int nt = 0; nt < 3; ++nt) {
    int ocl = wn * 48 + nt * 16 + (lane & 15);
    float bv = qb[o0 + ocl];
    unsigned short* ob = pre + ((size_t)bz * C3 + o0 + ocl) * HWC + p0;
#pragma unroll
    for (int mt = 0; mt < 4; ++mt) {
      f32x4 v = acc[mt][nt];
      ushort4 u;
      u.x = f2bf(v[0] + bv); u.y = f2bf(v[1] + bv);
      u.z = f2bf(v[2] + bv); u.w = f2bf(v[3] + bv);
      *reinterpret_cast<ushort4*>(ob + wm * 64 + mt * 16 + (lane >> 4) * 4) = u;
    }
  }
}

// K2: depthwise 3x3 + bias, all 288 ch bf16. Tile 32 rows x 256 cols. grid (288, 8, bc).
__global__ __launch_bounds__(256) void k2_dw(
    const unsigned short* __restrict__ pre, const float* __restrict__ dww,
    const float* __restrict__ dwb, unsigned short* __restrict__ dwo)
{
  __shared__ float s[34 * 268];
  const int t = threadIdx.x;
  const int c3 = blockIdx.x;
  const int h0 = blockIdx.y * 32;
  const int bz = blockIdx.z;
  const size_t choff = ((size_t)bz * C3 + c3) * HWC;
  const int rt = t >> 6, col4 = (t & 63) * 4;

#pragma unroll
  for (int r = 0; r < 9; ++r) {
    int row = r * 4 + rt;
    if (row < 34) {
      int hh = h0 + row - 1;
      float4 v = make_float4(0.f, 0.f, 0.f, 0.f);
      if (hh >= 0 && hh < HH) {
        ushort4 u = *reinterpret_cast<const ushort4*>(pre + choff + hh * WW + col4);
        v = make_float4(bf2f(u.x), bf2f(u.y), bf2f(u.z), bf2f(u.w));
      }
      *reinterpret_cast<float4*>(&s[row * 268 + 4 + col4]) = v;
    }
  }
  if (t < 34) { s[t * 268 + 3] = 0.f; s[t * 268 + 260] = 0.f; }
  __syncthreads();

  float wg[9];
#pragma unroll
  for (int i = 0; i < 9; ++i) wg[i] = dww[c3 * 9 + i];
  const float bias = dwb[c3];

#pragma unroll
  for (int rr = 0; rr < 8; ++rr) {
    int orow = rr * 4 + rt;
    float a0 = bias, a1 = bias, a2 = bias, a3 = bias;
#pragma unroll
    for (int dy = 0; dy < 3; ++dy) {
      const float* rowp = &s[(orow + dy) * 268 + 4 + col4];
      float4 rA = *reinterpret_cast<const float4*>(rowp - 4);
      float4 rB = *reinterpret_cast<const float4*>(rowp);
      float4 rC = *reinterpret_cast<const float4*>(rowp + 4);
      float w0 = wg[dy * 3 + 0], w1 = wg[dy * 3 + 1], w2 = wg[dy * 3 + 2];
      a0 = fmaf(rA.w, w0, fmaf(rB.x, w1, fmaf(rB.y, w2, a0)));
      a1 = fmaf(rB.x, w0, fmaf(rB.y, w1, fmaf(rB.z, w2, a1)));
      a2 = fmaf(rB.y, w0, fmaf(rB.z, w1, fmaf(rB.w, w2, a2)));
      a3 = fmaf(rB.z, w0, fmaf(rB.w, w1, fmaf(rC.x, w2, a3)));
    }
    ushort4 u;
    u.x = f2bf(a0); u.y = f2bf(a1); u.z = f2bf(a2); u.w = f2bf(a3);
    *reinterpret_cast<ushort4*>((unsigned short*)dwo + choff + (h0 + orow) * WW + col4) = u;
  }
}

// K3: partial Gram per (c, head, b) from bf16 q,k; + sumsq via atomics.
__global__ __launch_bounds__(256) void k3_gram(
    const unsigned short* __restrict__ dwo, float* __restrict__ gpart,
    float* __restrict__ ssq)
{
  __shared__ float qs[256 * 32];
  __shared__ float ks[256 * 32];
  const int t = threadIdx.x;
  const int c = blockIdx.x, head = blockIdx.y, bz = blockIdx.z;
  const unsigned short* qp = dwo + ((size_t)bz * C3 + c) * HWC + head * W2;
  const unsigned short* kp = dwo + ((size_t)bz * C3 + CC + c) * HWC + head * W2;
#pragma unroll
  for (int it = 0; it < 8; ++it) {
    int lin = it * 256 + t;
    int h = lin >> 3, j4 = (lin & 7) * 4;
    ushort4 qu = *reinterpret_cast<const ushort4*>(qp + h * WW + j4);
    ushort4 ku = *reinterpret_cast<const ushort4*>(kp + h * WW + j4);
    *reinterpret_cast<float4*>(&qs[h * 32 + j4]) =
        make_float4(bf2f(qu.x), bf2f(qu.y), bf2f(qu.z), bf2f(qu.w));
    *reinterpret_cast<float4*>(&ks[h * 32 + j4]) =
        make_float4(bf2f(ku.x), bf2f(ku.y), bf2f(ku.z), bf2f(ku.w));
  }
  __syncthreads();
  const int i = t & 31, jg = t >> 5;
  float a0 = 0, a1 = 0, a2 = 0, a3 = 0;
  for (int h = 0; h < 256; ++h) {
    float qv = qs[h * 32 + i];
    float4 kv = *reinterpret_cast<const float4*>(&ks[h * 32 + jg * 4]);
    a0 = fmaf(qv, kv.x, a0); a1 = fmaf(qv, kv.y, a1);
    a2 = fmaf(qv, kv.z, a2); a3 = fmaf(qv, kv.w, a3);
  }
  float* gp = gpart + (((size_t)bz * NHEADS + head) * CC + c) * 1024;
  gp[(jg * 4 + 0) * 32 + i] = a0;
  gp[(jg * 4 + 1) * 32 + i] = a1;
  gp[(jg * 4 + 2) * 32 + i] = a2;
  gp[(jg * 4 + 3) * 32 + i] = a3;
  if (t < 64) {
    const float* src = (t < 32) ? qs : ks;
    const int col = t & 31;
    float ssum = 0;
    for (int h = 0; h < 256; ++h) { float v = src[h * 32 + col]; ssum = fmaf(v, v, ssum); }
    atomicAdd(&ssq[((size_t)bz * 2 + (t >> 5)) * 256 + head * W2 + col], ssum);
  }
}

// K4: reduce Gram over c, normalize, temperature, softmax. grid (8, bc).
__global__ __launch_bounds__(256) void k4_attn(
    const float* __restrict__ gpart, const float* __restrict__ ssq,
    const float* __restrict__ temp, float* __restrict__ attn)
{
  __shared__ float lg[1024];
  const int t = threadIdx.x;
  const int head = blockIdx.x, bz = blockIdx.y;
  const float* gp = gpart + ((size_t)bz * NHEADS + head) * CC * 1024;
  float a0 = 0, a1 = 0, a2 = 0, a3 = 0;
  for (int c = 0; c < CC; ++c) {
    const float* g = gp + c * 1024;
    a0 += g[t]; a1 += g[t + 256]; a2 += g[t + 512]; a3 += g[t + 768];
  }
  lg[t] = a0; lg[t + 256] = a1; lg[t + 512] = a2; lg[t + 768] = a3;
  __syncthreads();
  if (t < 32) {
    const int i = t;
    const float* sq_ = ssq + (size_t)bz * 2 * 256 + head * W2;
    const float* sk_ = ssq + ((size_t)bz * 2 + 1) * 256 + head * W2;
    float invq = 1.f / fmaxf(sqrtf(sq_[i]), 1e-12f);
    float tpq = temp[head] * invq;
    float row[32];
    float m = -1e30f;
#pragma unroll
    for (int j = 0; j < 32; ++j) {
      float invk = 1.f / fmaxf(sqrtf(sk_[j]), 1e-12f);
      float v = lg[j * 32 + i] * tpq * invk;
      row[j] = v;
      m = fmaxf(m, v);
    }
    float ssum = 0;
#pragma unroll
    for (int j = 0; j < 32; ++j) { row[j] = expf(row[j] - m); ssum += row[j]; }
    float inv = 1.f / ssum;
    float* ap = attn + ((size_t)bz * NHEADS + head) * 1024 + i * 32;
#pragma unroll
    for (int j = 0; j < 32; ++j) ap[j] = row[j] * inv;
  }
}

// K5: out = proj(attn @ v) + proj_b. grid (8, 64, bc), 4 h-rows per block.
__global__ __launch_bounds__(256) void k5_out(
    const unsigned short* __restrict__ dwo, const float* __restrict__ attn,
    const float* __restrict__ pw, const float* __restrict__ pb,
    float* __restrict__ out, int b0)
{
  __shared__ float pwt[96 * 100];
  __shared__ float vs[96 * 32];
  __shared__ float tl[96 * 32];
  const int t = threadIdx.x;
  const int head = blockIdx.x, hb = blockIdx.y, bz = blockIdx.z;
  const int i = t & 31, cg = t >> 5;

#pragma unroll
  for (int r = 0; r < 36; ++r) {
    int lin = r * 256 + t;
    int o = lin / 96, c = lin - o * 96;
    pwt[c * 100 + o] = pw[lin];
  }
  float atr[32];
  {
    const float* ap = attn + ((size_t)bz * NHEADS + head) * 1024 + i * 32;
#pragma unroll
    for (int j4 = 0; j4 < 8; ++j4) {
      float4 a = *reinterpret_cast<const float4*>(ap + j4 * 4);
      atr[j4 * 4 + 0] = a.x; atr[j4 * 4 + 1] = a.y;
      atr[j4 * 4 + 2] = a.z; atr[j4 * 4 + 3] = a.w;
    }
  }
  float pbr[12];
#pragma unroll
  for (int oo = 0; oo < 12; ++oo) pbr[oo] = pb[cg * 12 + oo];
  const unsigned short* vbase = dwo + ((size_t)bz * C3 + 2 * CC) * HWC + head * W2;
  __syncthreads();

  for (int r = 0; r < 4; ++r) {
    if (r) __syncthreads();
    const int h = hb * 4 + r;
#pragma unroll
    for (int it = 0; it < 3; ++it) {
      int lin = it * 256 + t;
      int c = lin >> 3, j4 = (lin & 7) * 4;
      ushort4 u = *reinterpret_cast<const ushort4*>(vbase + (size_t)c * HWC + h * WW + j4);
      *reinterpret_cast<float4*>(&vs[c * 32 + j4]) =
          make_float4(bf2f(u.x), bf2f(u.y), bf2f(u.z), bf2f(u.w));
    }
    __syncthreads();
    float acc[12];
#pragma unroll
    for (int cc = 0; cc < 12; ++cc) {
      const float* vp = &vs[(cg * 12 + cc) * 32];
      float a = 0.f;
#pragma unroll
      for (int j4 = 0; j4 < 8; ++j4) {
        float4 vv = *reinterpret_cast<const float4*>(vp + j4 * 4);
        a = fmaf(vv.x, atr[j4 * 4 + 0], a);
        a = fmaf(vv.y, atr[j4 * 4 + 1], a);
        a = fmaf(vv.z, atr[j4 * 4 + 2], a);
        a = fmaf(vv.w, atr[j4 * 4 + 3], a);
      }
      acc[cc] = a;
    }
#pragma unroll
    for (int cc = 0; cc < 12; ++cc) tl[(cg * 12 + cc) * 32 + i] = acc[cc];
    __syncthreads();
    float oacc[12];
#pragma unroll
    for (int oo = 0; oo < 12; ++oo) oacc[oo] = pbr[oo];
    for (int c = 0; c < 96; ++c) {
      float tv = tl[c * 32 + i];
      const float* pp = &pwt[c * 100 + cg * 12];
      float4 w0 = *reinterpret_cast<const float4*>(pp);
      float4 w1 = *reinterpret_cast<const float4*>(pp + 4);
      float4 w2 = *reinterpret_cast<const float4*>(pp + 8);
      oacc[0] = fmaf(w0.x, tv, oacc[0]);  oacc[1] = fmaf(w0.y, tv, oacc[1]);
      oacc[2] = fmaf(w0.z, tv, oacc[2]);  oacc[3] = fmaf(w0.w, tv, oacc[3]);
      oacc[4] = fmaf(w1.x, tv, oacc[4]);  oacc[5] = fmaf(w1.y, tv, oacc[5]);
      oacc[6] = fmaf(w1.z, tv, oacc[6]);  oacc[7] = fmaf(w1.w, tv, oacc[7]);
      oacc[8] = fmaf(w2.x, tv, oacc[8]);  oacc[9] = fmaf(w2.y, tv, oacc[9]);
      oacc[10] = fmaf(w2.z, tv, oacc[10]); oacc[11] = fmaf(w2.w, tv, oacc[11]);
    }
    float* ob = out + ((size_t)(b0 + bz) * CC + cg * 12) * HWC + h * WW + head * W2 + i;
#pragma unroll
    for (int oo = 0; oo < 12; ++oo) ob[(size_t)oo * HWC] = oacc[oo];
  }
}

extern "C" void kernel_launch(void* const* d_in, const int* in_sizes, int n_in,
                              void* d_out, int out_size, void* d_ws, size_t ws_size,
                              hipStream_t stream)
{
  const float* x      = (const float*)d_in[0];
  const float* qkv_w  = (const float*)d_in[1];
  const float* qkv_b  = (const float*)d_in[2];
  const float* dw_w   = (const float*)d_in[3];
  const float* dw_b   = (const float*)d_in[4];
  const float* proj_w = (const float*)d_in[5];
  const float* proj_b = (const float*)d_in[6];
  const float* temp   = (const float*)d_in[7];
  float* out = (float*)d_out;

  const size_t per_pre  = (size_t)C3 * HWC * 2;             // bf16, 37.7 MB
  const size_t per_gp   = (size_t)NHEADS * CC * 1024 * 4;   // 3.1 MB
  const size_t per_ssq  = (size_t)2 * 256 * 4;
  const size_t per_attn = (size_t)NHEADS * 1024 * 4;
  const size_t per_b = per_pre * 2 + per_gp + per_ssq + per_attn;

  int bc = 4;
  while (bc > 1 && per_b * (size_t)bc > ws_size) bc >>= 1;

  char* p = (char*)d_ws;
  unsigned short* pre = (unsigned short*)p; p += per_pre * bc;
  unsigned short* dwo = (unsigned short*)p; p += per_pre * bc;
  float* gpart = (float*)p; p += per_gp * bc;
  float* ssq   = (float*)p; p += per_ssq * bc;
  float* attn  = (float*)p; p += per_attn * bc;

  for (int b0 = 0; b0 < 4; b0 += bc) {
    k1_qkv_mfma<<<dim3(512, 3, bc), 256, 0, stream>>>(x, qkv_w, qkv_b, pre, b0);
    k2_dw<<<dim3(C3, 8, bc), 256, 0, stream>>>(pre, dw_w, dw_b, dwo);
    hipMemsetAsync(ssq, 0, per_ssq * bc, stream);
    k3_gram<<<dim3(CC, NHEADS, bc), 256, 0, stream>>>(dwo, gpart, ssq);
    k4_attn<<<dim3(NHEADS, bc), 256, 0, stream>>>(gpart, ssq, temp, attn);
    k5_out<<<dim3(NHEADS, 64, bc), 256, 0, stream>>>(dwo, attn, proj_w, proj_b, out, b0);
  }
}

// Round 4
// 347.693 us; speedup vs baseline: 2.2704x; 1.1741x over previous
//
#include <hip/hip_runtime.h>

#define CC 96
#define C3 288
#define HH 256
#define WW 256
#define HWC 65536
#define NHEADS 8
#define W2 32

typedef __bf16 bf16x8 __attribute__((ext_vector_type(8)));
typedef float f32x4 __attribute__((ext_vector_type(4)));
typedef unsigned short us8v __attribute__((ext_vector_type(8)));

__device__ __forceinline__ float bf2f(unsigned short u) {
  return __uint_as_float(((unsigned)u) << 16);
}
__device__ __forceinline__ unsigned short f2bf(float f) {
  unsigned u = __float_as_uint(f);
  unsigned r = u + 0x7fffu + ((u >> 16) & 1u);
  return (unsigned short)(r >> 16);
}

// K1: qkv conv1x1 via bf16 MFMA. grid (512, 3, bc), block 256 (4 waves).
// Tile 128px x 96oc, K=96. LDS pitch 106 (53 dw: writes 2-way, frag reads clean).
// Epilogue: bias -> tD[oc][132] bf16 in LDS -> coalesced ushort8 global stores.
__global__ __launch_bounds__(256) void k1_qkv_mfma(
    const float* __restrict__ x, const float* __restrict__ qw,
    const float* __restrict__ qb, unsigned short* __restrict__ pre, int b0)
{
  __shared__ __align__(16) char smem[47488];
  unsigned short* As = (unsigned short*)smem;            // [128][106]
  unsigned short* Ws = (unsigned short*)(smem + 27136);  // [96][106]
  unsigned short* tD = (unsigned short*)smem;            // [96][132] (reuse)
  const int t = threadIdx.x;
  const int p0 = blockIdx.x * 128;
  const int o0 = blockIdx.y * 96;
  const int bz = blockIdx.z;
  const float* xb = x + (size_t)(b0 + bz) * CC * HWC;

#pragma unroll
  for (int r = 0; r < 6; ++r) {
    int lin = r * 256 + t;
    int icp = lin >> 5;            // 0..47 channel pairs
    int p4 = (lin & 31) * 4;       // 0..124
    float4 v0 = *reinterpret_cast<const float4*>(xb + (size_t)(2 * icp) * HWC + p0 + p4);
    float4 v1 = *reinterpret_cast<const float4*>(xb + (size_t)(2 * icp + 1) * HWC + p0 + p4);
    float a0[4] = {v0.x, v0.y, v0.z, v0.w};
    float a1[4] = {v1.x, v1.y, v1.z, v1.w};
#pragma unroll
    for (int j = 0; j < 4; ++j) {
      unsigned pk = (unsigned)f2bf(a0[j]) | ((unsigned)f2bf(a1[j]) << 16);
      *reinterpret_cast<unsigned*>(&As[(p4 + j) * 106 + 2 * icp]) = pk;
    }
  }
#pragma unroll
  for (int r = 0; r < 9; ++r) {
    int lin = r * 256 + t;
    int oc = lin / 24;
    int ic4 = (lin - oc * 24) * 4;
    float4 w = *reinterpret_cast<const float4*>(qw + (size_t)(o0 + oc) * 96 + ic4);
    ushort4 u;
    u.x = f2bf(w.x); u.y = f2bf(w.y); u.z = f2bf(w.z); u.w = f2bf(w.w);
    *reinterpret_cast<ushort4*>(&Ws[oc * 106 + ic4]) = u;
  }
  __syncthreads();

  const int wave = t >> 6, lane = t & 63;
  const int wm = wave & 1, wn = wave >> 1;
  const int row = lane & 15, kg = lane >> 4;

  f32x4 acc[4][3];
#pragma unroll
  for (int mt = 0; mt < 4; ++mt)
#pragma unroll
    for (int nt = 0; nt < 3; ++nt) acc[mt][nt] = (f32x4){0.f, 0.f, 0.f, 0.f};

#pragma unroll
  for (int kk = 0; kk < 3; ++kk) {
    bf16x8 a[4], b[3];
#pragma unroll
    for (int mt = 0; mt < 4; ++mt)
      a[mt] = *reinterpret_cast<const bf16x8*>(
          &As[(wm * 64 + mt * 16 + row) * 106 + kk * 32 + kg * 8]);
#pragma unroll
    for (int nt = 0; nt < 3; ++nt)
      b[nt] = *reinterpret_cast<const bf16x8*>(
          &Ws[(wn * 48 + nt * 16 + row) * 106 + kk * 32 + kg * 8]);
#pragma unroll
    for (int mt = 0; mt < 4; ++mt)
#pragma unroll
      for (int nt = 0; nt < 3; ++nt)
        acc[mt][nt] = __builtin_amdgcn_mfma_f32_16x16x32_bf16(
            a[mt], b[nt], acc[mt][nt], 0, 0, 0);
  }
  __syncthreads();   // all frag reads done; reuse LDS as tD

#pragma unroll
  for (int nt = 0; nt < 3; ++nt) {
    int ocl = wn * 48 + nt * 16 + row;
    float bv = qb[o0 + ocl];
#pragma unroll
    for (int mt = 0; mt < 4; ++mt) {
      int pxl = wm * 64 + mt * 16 + kg * 4;
      f32x4 v = acc[mt][nt];
      unsigned pk0 = (unsigned)f2bf(v[0] + bv) | ((unsigned)f2bf(v[1] + bv) << 16);
      unsigned pk1 = (unsigned)f2bf(v[2] + bv) | ((unsigned)f2bf(v[3] + bv) << 16);
      *reinterpret_cast<unsigned*>(&tD[ocl * 132 + pxl]) = pk0;
      *reinterpret_cast<unsigned*>(&tD[ocl * 132 + pxl + 2]) = pk1;
    }
  }
  __syncthreads();
  unsigned short* preb = pre + ((size_t)bz * C3 + o0) * HWC + p0;
#pragma unroll
  for (int r = 0; r < 6; ++r) {
    int lin = r * 256 + t;
    int oc = lin >> 4, ch = lin & 15;
    us8v v = *reinterpret_cast<const us8v*>(&tD[oc * 132 + ch * 8]);
    *reinterpret_cast<us8v*>(preb + (size_t)oc * HWC + ch * 8) = v;
  }
}

// K2: depthwise 3x3 + bias, all 288 ch bf16. Tile 32 rows x 256 cols. grid (288, 8, bc).
__global__ __launch_bounds__(256) void k2_dw(
    const unsigned short* __restrict__ pre, const float* __restrict__ dww,
    const float* __restrict__ dwb, unsigned short* __restrict__ dwo)
{
  __shared__ float s[34 * 268];
  const int t = threadIdx.x;
  const int c3 = blockIdx.x;
  const int h0 = blockIdx.y * 32;
  const int bz = blockIdx.z;
  const size_t choff = ((size_t)bz * C3 + c3) * HWC;
  const int rt = t >> 6, col4 = (t & 63) * 4;

#pragma unroll
  for (int r = 0; r < 9; ++r) {
    int row = r * 4 + rt;
    if (row < 34) {
      int hh = h0 + row - 1;
      float4 v = make_float4(0.f, 0.f, 0.f, 0.f);
      if (hh >= 0 && hh < HH) {
        ushort4 u = *reinterpret_cast<const ushort4*>(pre + choff + hh * WW + col4);
        v = make_float4(bf2f(u.x), bf2f(u.y), bf2f(u.z), bf2f(u.w));
      }
      *reinterpret_cast<float4*>(&s[row * 268 + 4 + col4]) = v;
    }
  }
  if (t < 34) { s[t * 268 + 3] = 0.f; s[t * 268 + 260] = 0.f; }
  __syncthreads();

  float wg[9];
#pragma unroll
  for (int i = 0; i < 9; ++i) wg[i] = dww[c3 * 9 + i];
  const float bias = dwb[c3];

#pragma unroll
  for (int rr = 0; rr < 8; ++rr) {
    int orow = rr * 4 + rt;
    float a0 = bias, a1 = bias, a2 = bias, a3 = bias;
#pragma unroll
    for (int dy = 0; dy < 3; ++dy) {
      const float* rowp = &s[(orow + dy) * 268 + 4 + col4];
      float4 rA = *reinterpret_cast<const float4*>(rowp - 4);
      float4 rB = *reinterpret_cast<const float4*>(rowp);
      float4 rC = *reinterpret_cast<const float4*>(rowp + 4);
      float w0 = wg[dy * 3 + 0], w1 = wg[dy * 3 + 1], w2 = wg[dy * 3 + 2];
      a0 = fmaf(rA.w, w0, fmaf(rB.x, w1, fmaf(rB.y, w2, a0)));
      a1 = fmaf(rB.x, w0, fmaf(rB.y, w1, fmaf(rB.z, w2, a1)));
      a2 = fmaf(rB.y, w0, fmaf(rB.z, w1, fmaf(rB.w, w2, a2)));
      a3 = fmaf(rB.z, w0, fmaf(rB.w, w1, fmaf(rC.x, w2, a3)));
    }
    ushort4 u;
    u.x = f2bf(a0); u.y = f2bf(a1); u.z = f2bf(a2); u.w = f2bf(a3);
    *reinterpret_cast<ushort4*>((unsigned short*)dwo + choff + (h0 + orow) * WW + col4) = u;
  }
}

// K3: partial Gram per (c, head, b) from bf16 q,k; + sumsq via atomics.
__global__ __launch_bounds__(256) void k3_gram(
    const unsigned short* __restrict__ dwo, float* __restrict__ gpart,
    float* __restrict__ ssq)
{
  __shared__ float qs[256 * 32];
  __shared__ float ks[256 * 32];
  const int t = threadIdx.x;
  const int c = blockIdx.x, head = blockIdx.y, bz = blockIdx.z;
  const unsigned short* qp = dwo + ((size_t)bz * C3 + c) * HWC + head * W2;
  const unsigned short* kp = dwo + ((size_t)bz * C3 + CC + c) * HWC + head * W2;
#pragma unroll
  for (int it = 0; it < 8; ++it) {
    int lin = it * 256 + t;
    int h = lin >> 3, j4 = (lin & 7) * 4;
    ushort4 qu = *reinterpret_cast<const ushort4*>(qp + h * WW + j4);
    ushort4 ku = *reinterpret_cast<const ushort4*>(kp + h * WW + j4);
    *reinterpret_cast<float4*>(&qs[h * 32 + j4]) =
        make_float4(bf2f(qu.x), bf2f(qu.y), bf2f(qu.z), bf2f(qu.w));
    *reinterpret_cast<float4*>(&ks[h * 32 + j4]) =
        make_float4(bf2f(ku.x), bf2f(ku.y), bf2f(ku.z), bf2f(ku.w));
  }
  __syncthreads();
  const int i = t & 31, jg = t >> 5;
  float a0 = 0, a1 = 0, a2 = 0, a3 = 0;
  for (int h = 0; h < 256; ++h) {
    float qv = qs[h * 32 + i];
    float4 kv = *reinterpret_cast<const float4*>(&ks[h * 32 + jg * 4]);
    a0 = fmaf(qv, kv.x, a0); a1 = fmaf(qv, kv.y, a1);
    a2 = fmaf(qv, kv.z, a2); a3 = fmaf(qv, kv.w, a3);
  }
  float* gp = gpart + (((size_t)bz * NHEADS + head) * CC + c) * 1024;
  gp[(jg * 4 + 0) * 32 + i] = a0;
  gp[(jg * 4 + 1) * 32 + i] = a1;
  gp[(jg * 4 + 2) * 32 + i] = a2;
  gp[(jg * 4 + 3) * 32 + i] = a3;
  if (t < 64) {
    const float* src = (t < 32) ? qs : ks;
    const int col = t & 31;
    float ssum = 0;
    for (int h = 0; h < 256; ++h) { float v = src[h * 32 + col]; ssum = fmaf(v, v, ssum); }
    atomicAdd(&ssq[((size_t)bz * 2 + (t >> 5)) * 256 + head * W2 + col], ssum);
  }
}

// K4a: reduce gpart over c -> g[b,h,1024]. grid (8, 8, bc), block 256.
__global__ __launch_bounds__(256) void k4a_reduce(
    const float* __restrict__ gpart, float* __restrict__ g)
{
  __shared__ float l[256];
  const int t = threadIdx.x;
  const int head = blockIdx.x, chunk = blockIdx.y, bz = blockIdx.z;
  const int e = chunk * 128 + (t & 127);
  const int half = t >> 7;
  const float* gp = gpart + (((size_t)bz * NHEADS + head) * CC + half * 48) * 1024 + e;
  float s = 0.f;
#pragma unroll 4
  for (int c = 0; c < 48; ++c) s += gp[(size_t)c * 1024];
  l[t] = s;
  __syncthreads();
  if (t < 128)
    g[((size_t)bz * NHEADS + head) * 1024 + chunk * 128 + t] = l[t] + l[t + 128];
}

// K4b: normalize + temperature + softmax. grid (8, bc), block 64 (one wave).
__global__ __launch_bounds__(64) void k4b_softmax(
    const float* __restrict__ g, const float* __restrict__ ssq,
    const float* __restrict__ temp, float* __restrict__ attn)
{
  const int t = threadIdx.x;
  const int head = blockIdx.x, bz = blockIdx.y;
  if (t >= 32) return;
  const int i = t;
  const float* gb = g + ((size_t)bz * NHEADS + head) * 1024;
  const float* sq_ = ssq + (size_t)bz * 512 + head * W2;
  const float* sk_ = ssq + (size_t)bz * 512 + 256 + head * W2;
  float invq = 1.f / fmaxf(sqrtf(sq_[i]), 1e-12f);
  float tpq = temp[head] * invq;
  float row[32];
  float m = -1e30f;
#pragma unroll
  for (int j = 0; j < 32; ++j) {
    float invk = 1.f / fmaxf(sqrtf(sk_[j]), 1e-12f);
    float v = gb[j * 32 + i] * tpq * invk;
    row[j] = v;
    m = fmaxf(m, v);
  }
  float ssum = 0;
#pragma unroll
  for (int j = 0; j < 32; ++j) { row[j] = expf(row[j] - m); ssum += row[j]; }
  float inv = 1.f / ssum;
  float* ap = attn + ((size_t)bz * NHEADS + head) * 1024 + i * 32;
#pragma unroll
  for (int j = 0; j < 32; ++j) ap[j] = row[j] * inv;
}

// K5a: t = attn @ v via MFMA. grid (384, bc), block 256 (4 waves).
// Rows R = c*256+h (contiguous in v memory), 64 rows/block, all 8 heads.
// A = v rows (K=j=32), B[j][i] = attn[i][j]. Output tbuf bf16 [c][pix].
__global__ __launch_bounds__(256) void k5a_attnv(
    const unsigned short* __restrict__ dwo, const float* __restrict__ attn,
    unsigned short* __restrict__ tbuf)
{
  __shared__ __align__(16) unsigned short vsm[64 * 264];     // v tile / tD reuse
  __shared__ __align__(16) unsigned short atn_s[256 * 40];   // attn bf16, pitch 40
  const int t = threadIdx.x;
  const int tile = blockIdx.x;
  const int bz = blockIdx.y;
  const size_t R0 = (size_t)tile * 64;
  const unsigned short* vsrc = dwo + ((size_t)bz * C3 + 2 * CC) * HWC + R0 * 256;

#pragma unroll
  for (int j = 0; j < 8; ++j) {
    int n = j * 256 + t;
    int row = n >> 5, c8 = n & 31;
    us8v v = *reinterpret_cast<const us8v*>(vsrc + n * 8);
    *reinterpret_cast<us8v*>(&vsm[row * 264 + c8 * 8]) = v;
  }
  {
    const float* ap = attn + (size_t)bz * 8192 + t * 32;   // row t = hd*32+i
    unsigned short* dst = &atn_s[t * 40];
#pragma unroll
    for (int k = 0; k < 8; ++k) {
      float4 a = *reinterpret_cast<const float4*>(ap + k * 4);
      ushort4 u;
      u.x = f2bf(a.x); u.y = f2bf(a.y); u.z = f2bf(a.z); u.w = f2bf(a.w);
      *reinterpret_cast<ushort4*>(dst + k * 4) = u;
    }
  }
  __syncthreads();

  const int wave = t >> 6, lane = t & 63;
  const int mrow = lane & 15, kg = lane >> 4;

  bf16x8 a[8], b[16];
#pragma unroll
  for (int hd = 0; hd < 8; ++hd)
    a[hd] = *reinterpret_cast<const bf16x8*>(
        &vsm[(wave * 16 + mrow) * 264 + hd * 32 + kg * 8]);
#pragma unroll
  for (int hd = 0; hd < 8; ++hd)
#pragma unroll
    for (int it = 0; it < 2; ++it)
      b[hd * 2 + it] = *reinterpret_cast<const bf16x8*>(
          &atn_s[(hd * 32 + it * 16 + mrow) * 40 + kg * 8]);

  f32x4 acc[16];
#pragma unroll
  for (int q = 0; q < 16; ++q) acc[q] = (f32x4){0.f, 0.f, 0.f, 0.f};
#pragma unroll
  for (int hd = 0; hd < 8; ++hd)
#pragma unroll
    for (int it = 0; it < 2; ++it)
      acc[hd * 2 + it] = __builtin_amdgcn_mfma_f32_16x16x32_bf16(
          a[hd], b[hd * 2 + it], acc[hd * 2 + it], 0, 0, 0);
  __syncthreads();   // all v reads done; reuse vsm as tD

#pragma unroll
  for (int hd = 0; hd < 8; ++hd)
#pragma unroll
    for (int it = 0; it < 2; ++it) {
      f32x4 v = acc[hd * 2 + it];
      int col = hd * 32 + it * 16 + mrow;
#pragma unroll
      for (int r = 0; r < 4; ++r)
        vsm[(wave * 16 + kg * 4 + r) * 264 + col] = f2bf(v[r]);
    }
  // wave-local readback (same rows this wave wrote) -> coalesced global
  unsigned short* tdst = tbuf + (size_t)bz * CC * HWC + R0 * 256;
#pragma unroll
  for (int k = 0; k < 8; ++k) {
    int n = k * 64 + lane;
    int rloc = n >> 5, c8 = n & 31;
    us8v v = *reinterpret_cast<const us8v*>(&vsm[(wave * 16 + rloc) * 264 + c8 * 8]);
    *reinterpret_cast<us8v*>(tdst + ((size_t)(wave * 16 + rloc)) * 256 + c8 * 8) = v;
  }
}

// K5b: out = proj(t) + pb via MFMA. grid (512, bc), block 256.
// A = tbuf bf16 [c][px], B = proj_w. fp32 epilogue via LDS transpose.
__global__ __launch_bounds__(256) void k5b_proj(
    const unsigned short* __restrict__ tbuf, const float* __restrict__ pw,
    const float* __restrict__ pb, float* __restrict__ out, int b0)
{
  __shared__ __align__(16) char smem[51712];
  unsigned short* As = (unsigned short*)smem;            // [128][106]
  unsigned short* Ws = (unsigned short*)(smem + 27136);  // [96][106]
  float* tD = (float*)smem;                               // [128][101]
  const int t = threadIdx.x;
  const int p0 = blockIdx.x * 128;
  const int bz = blockIdx.y;
  const unsigned short* tb = tbuf + (size_t)bz * CC * HWC;

#pragma unroll
  for (int r = 0; r < 6; ++r) {
    int lin = r * 256 + t;
    int icp = lin >> 5, p4 = (lin & 31) * 4;
    ushort4 u0 = *reinterpret_cast<const ushort4*>(tb + (size_t)(2 * icp) * HWC + p0 + p4);
    ushort4 u1 = *reinterpret_cast<const ushort4*>(tb + (size_t)(2 * icp + 1) * HWC + p0 + p4);
    unsigned short a0[4] = {u0.x, u0.y, u0.z, u0.w};
    unsigned short a1[4] = {u1.x, u1.y, u1.z, u1.w};
#pragma unroll
    for (int j = 0; j < 4; ++j) {
      unsigned pk = (unsigned)a0[j] | ((unsigned)a1[j] << 16);
      *reinterpret_cast<unsigned*>(&As[(p4 + j) * 106 + 2 * icp]) = pk;
    }
  }
#pragma unroll
  for (int r = 0; r < 9; ++r) {
    int lin = r * 256 + t;
    int oc = lin / 24;
    int ic4 = (lin - oc * 24) * 4;
    float4 w = *reinterpret_cast<const float4*>(pw + (size_t)oc * 96 + ic4);
    ushort4 u;
    u.x = f2bf(w.x); u.y = f2bf(w.y); u.z = f2bf(w.z); u.w = f2bf(w.w);
    *reinterpret_cast<ushort4*>(&Ws[oc * 106 + ic4]) = u;
  }
  __syncthreads();

  const int wave = t >> 6, lane = t & 63;
  const int wm = wave & 1, wn = wave >> 1;
  const int row = lane & 15, kg = lane >> 4;

  f32x4 acc[4][3];
#pragma unroll
  for (int mt = 0; mt < 4; ++mt)
#pragma unroll
    for (int nt = 0; nt < 3; ++nt) acc[mt][nt] = (f32x4){0.f, 0.f, 0.f, 0.f};

#pragma unroll
  for (int kk = 0; kk < 3; ++kk) {
    bf16x8 a[4], b[3];
#pragma unroll
    for (int mt = 0; mt < 4; ++mt)
      a[mt] = *reinterpret_cast<const bf16x8*>(
          &As[(wm * 64 + mt * 16 + row) * 106 + kk * 32 + kg * 8]);
#pragma unroll
    for (int nt = 0; nt < 3; ++nt)
      b[nt] = *reinterpret_cast<const bf16x8*>(
          &Ws[(wn * 48 + nt * 16 + row) * 106 + kk * 32 + kg * 8]);
#pragma unroll
    for (int mt = 0; mt < 4; ++mt)
#pragma unroll
      for (int nt = 0; nt < 3; ++nt)
        acc[mt][nt] = __builtin_amdgcn_mfma_f32_16x16x32_bf16(
            a[mt], b[nt], acc[mt][nt], 0, 0, 0);
  }
  __syncthreads();   // reuse LDS as tD fp32

#pragma unroll
  for (int nt = 0; nt < 3; ++nt) {
    int ocl = wn * 48 + nt * 16 + row;
    float bv = pb[ocl];
#pragma unroll
    for (int mt = 0; mt < 4; ++mt) {
      int pxl = wm * 64 + mt * 16 + kg * 4;
      f32x4 v = acc[mt][nt];
#pragma unroll
      for (int r = 0; r < 4; ++r)
        tD[(pxl + r) * 101 + ocl] = v[r] + bv;
    }
  }
  __syncthreads();
  float* ob = out + (size_t)(b0 + bz) * CC * HWC + p0;
#pragma unroll
  for (int r = 0; r < 12; ++r) {
    int lin = r * 256 + t;
    int o = lin >> 5, p4 = (lin & 31) * 4;
    float4 v;
    v.x = tD[(p4 + 0) * 101 + o];
    v.y = tD[(p4 + 1) * 101 + o];
    v.z = tD[(p4 + 2) * 101 + o];
    v.w = tD[(p4 + 3) * 101 + o];
    *reinterpret_cast<float4*>(ob + (size_t)o * HWC + p4) = v;
  }
}

extern "C" void kernel_launch(void* const* d_in, const int* in_sizes, int n_in,
                              void* d_out, int out_size, void* d_ws, size_t ws_size,
                              hipStream_t stream)
{
  const float* x      = (const float*)d_in[0];
  const float* qkv_w  = (const float*)d_in[1];
  const float* qkv_b  = (const float*)d_in[2];
  const float* dw_w   = (const float*)d_in[3];
  const float* dw_b   = (const float*)d_in[4];
  const float* proj_w = (const float*)d_in[5];
  const float* proj_b = (const float*)d_in[6];
  const float* temp   = (const float*)d_in[7];
  float* out = (float*)d_out;

  const size_t per_pre  = (size_t)C3 * HWC * 2;             // bf16, 37.7 MB
  const size_t per_gp   = (size_t)NHEADS * CC * 1024 * 4;   // 3.1 MB
  const size_t per_ssq  = (size_t)2 * 256 * 4;
  const size_t per_attn = (size_t)NHEADS * 1024 * 4;
  const size_t per_g    = (size_t)NHEADS * 1024 * 4;
  const size_t per_b = per_pre * 2 + per_gp + per_ssq + per_attn + per_g;

  int bc = 4;
  while (bc > 1 && per_b * (size_t)bc > ws_size) bc >>= 1;

  char* p = (char*)d_ws;
  unsigned short* pre = (unsigned short*)p; p += per_pre * bc;
  unsigned short* dwo = (unsigned short*)p; p += per_pre * bc;
  float* gpart = (float*)p; p += per_gp * bc;
  float* ssq   = (float*)p; p += per_ssq * bc;
  float* attn  = (float*)p; p += per_attn * bc;
  float* g     = (float*)p; p += per_g * bc;
  // tbuf aliases pre (pre is dead after k2; tbuf needs 12.6 MB/batch < 37.7)
  unsigned short* tbuf = pre;

  for (int b0 = 0; b0 < 4; b0 += bc) {
    k1_qkv_mfma<<<dim3(512, 3, bc), 256, 0, stream>>>(x, qkv_w, qkv_b, pre, b0);
    k2_dw<<<dim3(C3, 8, bc), 256, 0, stream>>>(pre, dw_w, dw_b, dwo);
    hipMemsetAsync(ssq, 0, per_ssq * bc, stream);
    k3_gram<<<dim3(CC, NHEADS, bc), 256, 0, stream>>>(dwo, gpart, ssq);
    k4a_reduce<<<dim3(NHEADS, 8, bc), 256, 0, stream>>>(gpart, g);
    k4b_softmax<<<dim3(NHEADS, bc), 64, 0, stream>>>(g, ssq, temp, attn);
    k5a_attnv<<<dim3(384, bc), 256, 0, stream>>>(dwo, attn, tbuf);
    k5b_proj<<<dim3(512, bc), 256, 0, stream>>>(tbuf, proj_w, proj_b, out, b0);
  }
}

// Round 5
// 318.221 us; speedup vs baseline: 2.4807x; 1.0926x over previous
//
#include <hip/hip_runtime.h>

#define CC 96
#define C3 288
#define HH 256
#define WW 256
#define HWC 65536
#define NHEADS 8
#define W2 32

typedef __bf16 bf16x8 __attribute__((ext_vector_type(8)));
typedef float f32x4 __attribute__((ext_vector_type(4)));
typedef unsigned short us8v __attribute__((ext_vector_type(8)));

__device__ __forceinline__ float bf2f(unsigned short u) {
  return __uint_as_float(((unsigned)u) << 16);
}
__device__ __forceinline__ unsigned short f2bf(float f) {
  unsigned u = __float_as_uint(f);
  unsigned r = u + 0x7fffu + ((u >> 16) & 1u);
  return (unsigned short)(r >> 16);
}

// K1: qkv conv1x1 via bf16 MFMA. grid (512, 3, bc), block 256 (4 waves).
// Two-phase staging: all 21 global loads -> regs, then cvt+LDS-write.
__global__ __launch_bounds__(256) void k1_qkv_mfma(
    const float* __restrict__ x, const float* __restrict__ qw,
    const float* __restrict__ qb, unsigned short* __restrict__ pre, int b0)
{
  __shared__ __align__(16) char smem[47488];
  unsigned short* As = (unsigned short*)smem;            // [128][106]
  unsigned short* Ws = (unsigned short*)(smem + 27136);  // [96][106]
  unsigned short* tD = (unsigned short*)smem;            // [96][136] (reuse)
  const int t = threadIdx.x;
  const int p0 = blockIdx.x * 128;
  const int o0 = blockIdx.y * 96;
  const int bz = blockIdx.z;
  const float* xb = x + (size_t)(b0 + bz) * CC * HWC;

  // ---- phase 1: issue all loads ----
  float4 va0[6], va1[6];
#pragma unroll
  for (int r = 0; r < 6; ++r) {
    int lin = r * 256 + t;
    int icp = lin >> 5;            // 0..47 channel pairs
    int p4 = (lin & 31) * 4;       // 0..124
    va0[r] = *reinterpret_cast<const float4*>(xb + (size_t)(2 * icp) * HWC + p0 + p4);
    va1[r] = *reinterpret_cast<const float4*>(xb + (size_t)(2 * icp + 1) * HWC + p0 + p4);
  }
  float4 vw[9];
#pragma unroll
  for (int r = 0; r < 9; ++r) {
    int lin = r * 256 + t;
    int oc = lin / 24;
    int ic4 = (lin - oc * 24) * 4;
    vw[r] = *reinterpret_cast<const float4*>(qw + (size_t)(o0 + oc) * 96 + ic4);
  }
  __builtin_amdgcn_sched_barrier(0);
  // ---- phase 2: convert + LDS write ----
#pragma unroll
  for (int r = 0; r < 6; ++r) {
    int lin = r * 256 + t;
    int icp = lin >> 5;
    int p4 = (lin & 31) * 4;
    float a0[4] = {va0[r].x, va0[r].y, va0[r].z, va0[r].w};
    float a1[4] = {va1[r].x, va1[r].y, va1[r].z, va1[r].w};
#pragma unroll
    for (int j = 0; j < 4; ++j) {
      unsigned pk = (unsigned)f2bf(a0[j]) | ((unsigned)f2bf(a1[j]) << 16);
      *reinterpret_cast<unsigned*>(&As[(p4 + j) * 106 + 2 * icp]) = pk;
    }
  }
#pragma unroll
  for (int r = 0; r < 9; ++r) {
    int lin = r * 256 + t;
    int oc = lin / 24;
    int ic4 = (lin - oc * 24) * 4;
    ushort4 u;
    u.x = f2bf(vw[r].x); u.y = f2bf(vw[r].y); u.z = f2bf(vw[r].z); u.w = f2bf(vw[r].w);
    *reinterpret_cast<ushort4*>(&Ws[oc * 106 + ic4]) = u;
  }
  __syncthreads();

  const int wave = t >> 6, lane = t & 63;
  const int wm = wave & 1, wn = wave >> 1;
  const int row = lane & 15, kg = lane >> 4;

  f32x4 acc[4][3];
#pragma unroll
  for (int mt = 0; mt < 4; ++mt)
#pragma unroll
    for (int nt = 0; nt < 3; ++nt) acc[mt][nt] = (f32x4){0.f, 0.f, 0.f, 0.f};

#pragma unroll
  for (int kk = 0; kk < 3; ++kk) {
    bf16x8 a[4], b[3];
#pragma unroll
    for (int mt = 0; mt < 4; ++mt)
      a[mt] = *reinterpret_cast<const bf16x8*>(
          &As[(wm * 64 + mt * 16 + row) * 106 + kk * 32 + kg * 8]);
#pragma unroll
    for (int nt = 0; nt < 3; ++nt)
      b[nt] = *reinterpret_cast<const bf16x8*>(
          &Ws[(wn * 48 + nt * 16 + row) * 106 + kk * 32 + kg * 8]);
#pragma unroll
    for (int mt = 0; mt < 4; ++mt)
#pragma unroll
      for (int nt = 0; nt < 3; ++nt)
        acc[mt][nt] = __builtin_amdgcn_mfma_f32_16x16x32_bf16(
            a[mt], b[nt], acc[mt][nt], 0, 0, 0);
  }
  __syncthreads();   // all frag reads done; reuse LDS as tD

#pragma unroll
  for (int nt = 0; nt < 3; ++nt) {
    int ocl = wn * 48 + nt * 16 + row;
    float bv = qb[o0 + ocl];
#pragma unroll
    for (int mt = 0; mt < 4; ++mt) {
      int pxl = wm * 64 + mt * 16 + kg * 4;
      f32x4 v = acc[mt][nt];
      unsigned pk0 = (unsigned)f2bf(v[0] + bv) | ((unsigned)f2bf(v[1] + bv) << 16);
      unsigned pk1 = (unsigned)f2bf(v[2] + bv) | ((unsigned)f2bf(v[3] + bv) << 16);
      *reinterpret_cast<unsigned*>(&tD[ocl * 136 + pxl]) = pk0;
      *reinterpret_cast<unsigned*>(&tD[ocl * 136 + pxl + 2]) = pk1;
    }
  }
  __syncthreads();
  unsigned short* preb = pre + ((size_t)bz * C3 + o0) * HWC + p0;
#pragma unroll
  for (int r = 0; r < 6; ++r) {
    int lin = r * 256 + t;
    int oc = lin >> 4, ch = lin & 15;
    us8v v = *reinterpret_cast<const us8v*>(&tD[oc * 136 + ch * 8]);
    *reinterpret_cast<us8v*>(preb + (size_t)oc * HWC + ch * 8) = v;
  }
}

// K2: depthwise 3x3 + bias, 288 ch bf16. Tile 32x256. grid (288, 8, bc).
__global__ __launch_bounds__(256) void k2_dw(
    const unsigned short* __restrict__ pre, const float* __restrict__ dww,
    const float* __restrict__ dwb, unsigned short* __restrict__ dwo)
{
  __shared__ float s[34 * 268];
  const int t = threadIdx.x;
  const int c3 = blockIdx.x;
  const int h0 = blockIdx.y * 32;
  const int bz = blockIdx.z;
  const size_t choff = ((size_t)bz * C3 + c3) * HWC;
  const int rt = t >> 6, col4 = (t & 63) * 4;

  ushort4 uu[9];
#pragma unroll
  for (int r = 0; r < 9; ++r) {
    int row = r * 4 + rt;
    int hh = h0 + row - 1;
    uu[r] = make_ushort4(0, 0, 0, 0);
    if (row < 34 && hh >= 0 && hh < HH)
      uu[r] = *reinterpret_cast<const ushort4*>(pre + choff + hh * WW + col4);
  }
  __builtin_amdgcn_sched_barrier(0);
#pragma unroll
  for (int r = 0; r < 9; ++r) {
    int row = r * 4 + rt;
    if (row < 34) {
      *reinterpret_cast<float4*>(&s[row * 268 + 4 + col4]) =
          make_float4(bf2f(uu[r].x), bf2f(uu[r].y), bf2f(uu[r].z), bf2f(uu[r].w));
    }
  }
  if (t < 34) { s[t * 268 + 3] = 0.f; s[t * 268 + 260] = 0.f; }
  __syncthreads();

  float wg[9];
#pragma unroll
  for (int i = 0; i < 9; ++i) wg[i] = dww[c3 * 9 + i];
  const float bias = dwb[c3];

#pragma unroll
  for (int rr = 0; rr < 8; ++rr) {
    int orow = rr * 4 + rt;
    float a0 = bias, a1 = bias, a2 = bias, a3 = bias;
#pragma unroll
    for (int dy = 0; dy < 3; ++dy) {
      const float* rowp = &s[(orow + dy) * 268 + 4 + col4];
      float4 rA = *reinterpret_cast<const float4*>(rowp - 4);
      float4 rB = *reinterpret_cast<const float4*>(rowp);
      float4 rC = *reinterpret_cast<const float4*>(rowp + 4);
      float w0 = wg[dy * 3 + 0], w1 = wg[dy * 3 + 1], w2 = wg[dy * 3 + 2];
      a0 = fmaf(rA.w, w0, fmaf(rB.x, w1, fmaf(rB.y, w2, a0)));
      a1 = fmaf(rB.x, w0, fmaf(rB.y, w1, fmaf(rB.z, w2, a1)));
      a2 = fmaf(rB.y, w0, fmaf(rB.z, w1, fmaf(rB.w, w2, a2)));
      a3 = fmaf(rB.z, w0, fmaf(rB.w, w1, fmaf(rC.x, w2, a3)));
    }
    ushort4 u;
    u.x = f2bf(a0); u.y = f2bf(a1); u.z = f2bf(a2); u.w = f2bf(a3);
    *reinterpret_cast<ushort4*>((unsigned short*)dwo + choff + (h0 + orow) * WW + col4) = u;
  }
}

// K3: partial Gram per (c, head, b) from bf16 q,k; + sumsq via atomics.
__global__ __launch_bounds__(256) void k3_gram(
    const unsigned short* __restrict__ dwo, float* __restrict__ gpart,
    float* __restrict__ ssq)
{
  __shared__ float qs[256 * 32];
  __shared__ float ks[256 * 32];
  const int t = threadIdx.x;
  const int c = blockIdx.x, head = blockIdx.y, bz = blockIdx.z;
  const unsigned short* qp = dwo + ((size_t)bz * C3 + c) * HWC + head * W2;
  const unsigned short* kp = dwo + ((size_t)bz * C3 + CC + c) * HWC + head * W2;
  ushort4 qu[8], ku[8];
#pragma unroll
  for (int it = 0; it < 8; ++it) {
    int lin = it * 256 + t;
    int h = lin >> 3, j4 = (lin & 7) * 4;
    qu[it] = *reinterpret_cast<const ushort4*>(qp + h * WW + j4);
    ku[it] = *reinterpret_cast<const ushort4*>(kp + h * WW + j4);
  }
  __builtin_amdgcn_sched_barrier(0);
#pragma unroll
  for (int it = 0; it < 8; ++it) {
    int lin = it * 256 + t;
    int h = lin >> 3, j4 = (lin & 7) * 4;
    *reinterpret_cast<float4*>(&qs[h * 32 + j4]) =
        make_float4(bf2f(qu[it].x), bf2f(qu[it].y), bf2f(qu[it].z), bf2f(qu[it].w));
    *reinterpret_cast<float4*>(&ks[h * 32 + j4]) =
        make_float4(bf2f(ku[it].x), bf2f(ku[it].y), bf2f(ku[it].z), bf2f(ku[it].w));
  }
  __syncthreads();
  const int i = t & 31, jg = t >> 5;
  float a0 = 0, a1 = 0, a2 = 0, a3 = 0;
  for (int h = 0; h < 256; ++h) {
    float qv = qs[h * 32 + i];
    float4 kv = *reinterpret_cast<const float4*>(&ks[h * 32 + jg * 4]);
    a0 = fmaf(qv, kv.x, a0); a1 = fmaf(qv, kv.y, a1);
    a2 = fmaf(qv, kv.z, a2); a3 = fmaf(qv, kv.w, a3);
  }
  float* gp = gpart + (((size_t)bz * NHEADS + head) * CC + c) * 1024;
  gp[(jg * 4 + 0) * 32 + i] = a0;
  gp[(jg * 4 + 1) * 32 + i] = a1;
  gp[(jg * 4 + 2) * 32 + i] = a2;
  gp[(jg * 4 + 3) * 32 + i] = a3;
  if (t < 64) {
    const float* src = (t < 32) ? qs : ks;
    const int col = t & 31;
    float ssum = 0;
    for (int h = 0; h < 256; ++h) { float v = src[h * 32 + col]; ssum = fmaf(v, v, ssum); }
    atomicAdd(&ssq[((size_t)bz * 2 + (t >> 5)) * 256 + head * W2 + col], ssum);
  }
}

// K4a: reduce gpart over c -> g[b,h,1024]. grid (8, 8, bc), block 256.
__global__ __launch_bounds__(256) void k4a_reduce(
    const float* __restrict__ gpart, float* __restrict__ g)
{
  __shared__ float l[256];
  const int t = threadIdx.x;
  const int head = blockIdx.x, chunk = blockIdx.y, bz = blockIdx.z;
  const int e = chunk * 128 + (t & 127);
  const int half = t >> 7;
  const float* gp = gpart + (((size_t)bz * NHEADS + head) * CC + half * 48) * 1024 + e;
  float s = 0.f;
#pragma unroll 4
  for (int c = 0; c < 48; ++c) s += gp[(size_t)c * 1024];
  l[t] = s;
  __syncthreads();
  if (t < 128)
    g[((size_t)bz * NHEADS + head) * 1024 + chunk * 128 + t] = l[t] + l[t + 128];
}

// K4b: normalize + temperature + softmax. grid (8, bc), block 64.
__global__ __launch_bounds__(64) void k4b_softmax(
    const float* __restrict__ g, const float* __restrict__ ssq,
    const float* __restrict__ temp, float* __restrict__ attn)
{
  const int t = threadIdx.x;
  const int head = blockIdx.x, bz = blockIdx.y;
  if (t >= 32) return;
  const int i = t;
  const float* gb = g + ((size_t)bz * NHEADS + head) * 1024;
  const float* sq_ = ssq + (size_t)bz * 512 + head * W2;
  const float* sk_ = ssq + (size_t)bz * 512 + 256 + head * W2;
  float invq = 1.f / fmaxf(sqrtf(sq_[i]), 1e-12f);
  float tpq = temp[head] * invq;
  float row[32];
  float m = -1e30f;
#pragma unroll
  for (int j = 0; j < 32; ++j) {
    float invk = 1.f / fmaxf(sqrtf(sk_[j]), 1e-12f);
    float v = gb[j * 32 + i] * tpq * invk;
    row[j] = v;
    m = fmaxf(m, v);
  }
  float ssum = 0;
#pragma unroll
  for (int j = 0; j < 32; ++j) { row[j] = expf(row[j] - m); ssum += row[j]; }
  float inv = 1.f / ssum;
  float* ap = attn + ((size_t)bz * NHEADS + head) * 1024 + i * 32;
#pragma unroll
  for (int j = 0; j < 32; ++j) ap[j] = row[j] * inv;
}

// K5a: t = attn @ v via MFMA. grid (384, bc), block 256 (4 waves).
__global__ __launch_bounds__(256) void k5a_attnv(
    const unsigned short* __restrict__ dwo, const float* __restrict__ attn,
    unsigned short* __restrict__ tbuf)
{
  __shared__ __align__(16) unsigned short vsm[64 * 264];     // v tile / tD reuse
  __shared__ __align__(16) unsigned short atn_s[256 * 36];   // attn bf16, pitch 36
  const int t = threadIdx.x;
  const int tile = blockIdx.x;
  const int bz = blockIdx.y;
  const size_t R0 = (size_t)tile * 64;
  const unsigned short* vsrc = dwo + ((size_t)bz * C3 + 2 * CC) * HWC + R0 * 256;

  us8v vv[8];
#pragma unroll
  for (int j = 0; j < 8; ++j)
    vv[j] = *reinterpret_cast<const us8v*>(vsrc + (size_t)(j * 256 + t) * 8);
  float4 av[8];
  {
    const float* ap = attn + (size_t)bz * 8192 + t * 32;
#pragma unroll
    for (int k = 0; k < 8; ++k)
      av[k] = *reinterpret_cast<const float4*>(ap + k * 4);
  }
  __builtin_amdgcn_sched_barrier(0);
#pragma unroll
  for (int j = 0; j < 8; ++j) {
    int n = j * 256 + t;
    int row = n >> 5, c8 = n & 31;
    *reinterpret_cast<us8v*>(&vsm[row * 264 + c8 * 8]) = vv[j];
  }
#pragma unroll
  for (int k = 0; k < 8; ++k) {
    ushort4 u;
    u.x = f2bf(av[k].x); u.y = f2bf(av[k].y); u.z = f2bf(av[k].z); u.w = f2bf(av[k].w);
    *reinterpret_cast<ushort4*>(&atn_s[t * 36 + k * 4]) = u;
  }
  __syncthreads();

  const int wave = t >> 6, lane = t & 63;
  const int mrow = lane & 15, kg = lane >> 4;

  bf16x8 a[8], b[16];
#pragma unroll
  for (int hd = 0; hd < 8; ++hd)
    a[hd] = *reinterpret_cast<const bf16x8*>(
        &vsm[(wave * 16 + mrow) * 264 + hd * 32 + kg * 8]);
#pragma unroll
  for (int hd = 0; hd < 8; ++hd)
#pragma unroll
    for (int it = 0; it < 2; ++it)
      b[hd * 2 + it] = *reinterpret_cast<const bf16x8*>(
          &atn_s[(hd * 32 + it * 16 + mrow) * 36 + kg * 8]);

  f32x4 acc[16];
#pragma unroll
  for (int q = 0; q < 16; ++q) acc[q] = (f32x4){0.f, 0.f, 0.f, 0.f};
#pragma unroll
  for (int hd = 0; hd < 8; ++hd)
#pragma unroll
    for (int it = 0; it < 2; ++it)
      acc[hd * 2 + it] = __builtin_amdgcn_mfma_f32_16x16x32_bf16(
          a[hd], b[hd * 2 + it], acc[hd * 2 + it], 0, 0, 0);
  __syncthreads();   // all v reads done; reuse vsm as tD

#pragma unroll
  for (int hd = 0; hd < 8; ++hd)
#pragma unroll
    for (int it = 0; it < 2; ++it) {
      f32x4 v = acc[hd * 2 + it];
      int col = hd * 32 + it * 16 + mrow;
#pragma unroll
      for (int r = 0; r < 4; ++r)
        vsm[(wave * 16 + kg * 4 + r) * 264 + col] = f2bf(v[r]);
    }
  unsigned short* tdst = tbuf + (size_t)bz * CC * HWC + R0 * 256;
#pragma unroll
  for (int k = 0; k < 8; ++k) {
    int n = k * 64 + lane;
    int rloc = n >> 5, c8 = n & 31;
    us8v v = *reinterpret_cast<const us8v*>(&vsm[(wave * 16 + rloc) * 264 + c8 * 8]);
    *reinterpret_cast<us8v*>(tdst + ((size_t)(wave * 16 + rloc)) * 256 + c8 * 8) = v;
  }
}

// K5b: out = proj(t) + pb via MFMA. grid (512, bc), block 256.
// tD flipped to [o][p] pitch 132 fp32: float4 writes and reads, coalesced stores.
__global__ __launch_bounds__(256) void k5b_proj(
    const unsigned short* __restrict__ tbuf, const float* __restrict__ pw,
    const float* __restrict__ pb, float* __restrict__ out, int b0)
{
  __shared__ __align__(16) char smem[50688];
  unsigned short* As = (unsigned short*)smem;            // [128][106]
  unsigned short* Ws = (unsigned short*)(smem + 27136);  // [96][106]
  float* tD = (float*)smem;                               // [96][132] (reuse)
  const int t = threadIdx.x;
  const int p0 = blockIdx.x * 128;
  const int bz = blockIdx.y;
  const unsigned short* tb = tbuf + (size_t)bz * CC * HWC;

  us8v ua0[3], ua1[3];
#pragma unroll
  for (int r = 0; r < 3; ++r) {
    int lin = r * 256 + t;
    int icp = lin >> 4, p8 = (lin & 15) * 8;
    ua0[r] = *reinterpret_cast<const us8v*>(tb + (size_t)(2 * icp) * HWC + p0 + p8);
    ua1[r] = *reinterpret_cast<const us8v*>(tb + (size_t)(2 * icp + 1) * HWC + p0 + p8);
  }
  float4 vw[9];
#pragma unroll
  for (int r = 0; r < 9; ++r) {
    int lin = r * 256 + t;
    int oc = lin / 24;
    int ic4 = (lin - oc * 24) * 4;
    vw[r] = *reinterpret_cast<const float4*>(pw + (size_t)oc * 96 + ic4);
  }
  __builtin_amdgcn_sched_barrier(0);
#pragma unroll
  for (int r = 0; r < 3; ++r) {
    int lin = r * 256 + t;
    int icp = lin >> 4, p8 = (lin & 15) * 8;
#pragma unroll
    for (int j = 0; j < 8; ++j) {
      unsigned pk = (unsigned)ua0[r][j] | ((unsigned)ua1[r][j] << 16);
      *reinterpret_cast<unsigned*>(&As[(p8 + j) * 106 + 2 * icp]) = pk;
    }
  }
#pragma unroll
  for (int r = 0; r < 9; ++r) {
    int lin = r * 256 + t;
    int oc = lin / 24;
    int ic4 = (lin - oc * 24) * 4;
    ushort4 u;
    u.x = f2bf(vw[r].x); u.y = f2bf(vw[r].y); u.z = f2bf(vw[r].z); u.w = f2bf(vw[r].w);
    *reinterpret_cast<ushort4*>(&Ws[oc * 106 + ic4]) = u;
  }
  __syncthreads();

  const int wave = t >> 6, lane = t & 63;
  const int wm = wave & 1, wn = wave >> 1;
  const int row = lane & 15, kg = lane >> 4;

  f32x4 acc[4][3];
#pragma unroll
  for (int mt = 0; mt < 4; ++mt)
#pragma unroll
    for (int nt = 0; nt < 3; ++nt) acc[mt][nt] = (f32x4){0.f, 0.f, 0.f, 0.f};

#pragma unroll
  for (int kk = 0; kk < 3; ++kk) {
    bf16x8 a[4], b[3];
#pragma unroll
    for (int mt = 0; mt < 4; ++mt)
      a[mt] = *reinterpret_cast<const bf16x8*>(
          &As[(wm * 64 + mt * 16 + row) * 106 + kk * 32 + kg * 8]);
#pragma unroll
    for (int nt = 0; nt < 3; ++nt)
      b[nt] = *reinterpret_cast<const bf16x8*>(
          &Ws[(wn * 48 + nt * 16 + row) * 106 + kk * 32 + kg * 8]);
#pragma unroll
    for (int mt = 0; mt < 4; ++mt)
#pragma unroll
      for (int nt = 0; nt < 3; ++nt)
        acc[mt][nt] = __builtin_amdgcn_mfma_f32_16x16x32_bf16(
            a[mt], b[nt], acc[mt][nt], 0, 0, 0);
  }
  __syncthreads();   // reuse LDS as tD fp32 [o][p]

#pragma unroll
  for (int nt = 0; nt < 3; ++nt) {
    int ocl = wn * 48 + nt * 16 + row;
    float bv = pb[ocl];
#pragma unroll
    for (int mt = 0; mt < 4; ++mt) {
      int pxl = wm * 64 + mt * 16 + kg * 4;
      f32x4 v = acc[mt][nt];
      float4 w = make_float4(v[0] + bv, v[1] + bv, v[2] + bv, v[3] + bv);
      *reinterpret_cast<float4*>(&tD[ocl * 132 + pxl]) = w;
    }
  }
  __syncthreads();
  float* ob = out + (size_t)(b0 + bz) * CC * HWC + p0;
#pragma unroll
  for (int r = 0; r < 12; ++r) {
    int lin = r * 256 + t;
    int o = lin >> 5, p4 = (lin & 31) * 4;
    float4 v = *reinterpret_cast<const float4*>(&tD[o * 132 + p4]);
    *reinterpret_cast<float4*>(ob + (size_t)o * HWC + p4) = v;
  }
}

extern "C" void kernel_launch(void* const* d_in, const int* in_sizes, int n_in,
                              void* d_out, int out_size, void* d_ws, size_t ws_size,
                              hipStream_t stream)
{
  const float* x      = (const float*)d_in[0];
  const float* qkv_w  = (const float*)d_in[1];
  const float* qkv_b  = (const float*)d_in[2];
  const float* dw_w   = (const float*)d_in[3];
  const float* dw_b   = (const float*)d_in[4];
  const float* proj_w = (const float*)d_in[5];
  const float* proj_b = (const float*)d_in[6];
  const float* temp   = (const float*)d_in[7];
  float* out = (float*)d_out;

  const size_t per_pre  = (size_t)C3 * HWC * 2;             // bf16, 37.7 MB
  const size_t per_gp   = (size_t)NHEADS * CC * 1024 * 4;   // 3.1 MB
  const size_t per_ssq  = (size_t)2 * 256 * 4;
  const size_t per_attn = (size_t)NHEADS * 1024 * 4;
  const size_t per_g    = (size_t)NHEADS * 1024 * 4;
  const size_t per_b = per_pre * 2 + per_gp + per_ssq + per_attn + per_g;

  int bc = 4;
  while (bc > 1 && per_b * (size_t)bc > ws_size) bc >>= 1;

  char* p = (char*)d_ws;
  unsigned short* pre = (unsigned short*)p; p += per_pre * bc;
  unsigned short* dwo = (unsigned short*)p; p += per_pre * bc;
  float* gpart = (float*)p; p += per_gp * bc;
  float* ssq   = (float*)p; p += per_ssq * bc;
  float* attn  = (float*)p; p += per_attn * bc;
  float* g     = (float*)p; p += per_g * bc;
  unsigned short* tbuf = pre;   // pre dead after k2

  for (int b0 = 0; b0 < 4; b0 += bc) {
    k1_qkv_mfma<<<dim3(512, 3, bc), 256, 0, stream>>>(x, qkv_w, qkv_b, pre, b0);
    k2_dw<<<dim3(C3, 8, bc), 256, 0, stream>>>(pre, dw_w, dw_b, dwo);
    hipMemsetAsync(ssq, 0, per_ssq * bc, stream);
    k3_gram<<<dim3(CC, NHEADS, bc), 256, 0, stream>>>(dwo, gpart, ssq);
    k4a_reduce<<<dim3(NHEADS, 8, bc), 256, 0, stream>>>(gpart, g);
    k4b_softmax<<<dim3(NHEADS, bc), 64, 0, stream>>>(g, ssq, temp, attn);
    k5a_attnv<<<dim3(384, bc), 256, 0, stream>>>(dwo, attn, tbuf);
    k5b_proj<<<dim3(512, bc), 256, 0, stream>>>(tbuf, proj_w, proj_b, out, b0);
  }
}

// Round 6
// 297.797 us; speedup vs baseline: 2.6509x; 1.0686x over previous
//
#include <hip/hip_runtime.h>

#define CC 96
#define C3 288
#define HH 256
#define WW 256
#define HWC 65536
#define NHEADS 8
#define W2 32

typedef __bf16 bf16x8 __attribute__((ext_vector_type(8)));
typedef float f32x4 __attribute__((ext_vector_type(4)));
typedef unsigned short us8v __attribute__((ext_vector_type(8)));

__device__ __forceinline__ float bf2f(unsigned short u) {
  return __uint_as_float(((unsigned)u) << 16);
}
__device__ __forceinline__ unsigned short f2bf(float f) {
  unsigned u = __float_as_uint(f);
  unsigned r = u + 0x7fffu + ((u >> 16) & 1u);
  return (unsigned short)(r >> 16);
}

// K1 v3: qkv conv1x1 via bf16 MFMA, software-pipelined over 4 px-tiles/block.
// grid (128, 3, bc), block 256 (4 waves). W-frags in registers (loaded once);
// As double-buffered; tD aliases the just-consumed As buffer.
__global__ __launch_bounds__(256, 2) void k1_qkv_mfma(
    const float* __restrict__ x, const float* __restrict__ qw,
    const float* __restrict__ qb, unsigned short* __restrict__ pre, int b0)
{
  __shared__ __align__(16) unsigned short As2[2][128 * 106];
  const int t = threadIdx.x;
  const int o0 = blockIdx.y * 96;
  const int bz = blockIdx.z;
  const float* xb = x + (size_t)(b0 + bz) * CC * HWC;

  const int wave = t >> 6, lane = t & 63;
  const int wm = wave & 1, wn = wave >> 1;
  const int row = lane & 15, kg = lane >> 4;

  // ---- prologue: weight fragments + bias into registers ----
  bf16x8 bfr[3][3];   // [kk][nt]
  float bias[3];
#pragma unroll
  for (int nt = 0; nt < 3; ++nt) {
    int ocl = wn * 48 + nt * 16 + row;
    bias[nt] = qb[o0 + ocl];
#pragma unroll
    for (int kk = 0; kk < 3; ++kk) {
      const float* wp = qw + (size_t)(o0 + ocl) * 96 + kk * 32 + kg * 8;
      float4 w0 = *reinterpret_cast<const float4*>(wp);
      float4 w1 = *reinterpret_cast<const float4*>(wp + 4);
      us8v u;
      u[0] = f2bf(w0.x); u[1] = f2bf(w0.y); u[2] = f2bf(w0.z); u[3] = f2bf(w0.w);
      u[4] = f2bf(w1.x); u[5] = f2bf(w1.y); u[6] = f2bf(w1.z); u[7] = f2bf(w1.w);
      bfr[kk][nt] = *reinterpret_cast<bf16x8*>(&u);
    }
  }

  // staging index (constant across tiles)
  int sic[6], sp4[6];
#pragma unroll
  for (int r = 0; r < 6; ++r) {
    int lin = r * 256 + t;
    sic[r] = lin >> 5;          // channel pair 0..47
    sp4[r] = (lin & 31) * 4;    // px 0..124
  }

  int p0 = blockIdx.x * 512;
  // issue tile-0 loads
  float4 va0[6], va1[6];
#pragma unroll
  for (int r = 0; r < 6; ++r) {
    va0[r] = *reinterpret_cast<const float4*>(xb + (size_t)(2 * sic[r]) * HWC + p0 + sp4[r]);
    va1[r] = *reinterpret_cast<const float4*>(xb + (size_t)(2 * sic[r] + 1) * HWC + p0 + sp4[r]);
  }

  for (int i = 0; i < 4; ++i) {
    unsigned short* Ac = As2[i & 1];
    // cvt + LDS write (consumes va regs; compiler inserts vmcnt waits)
#pragma unroll
    for (int r = 0; r < 6; ++r) {
      float a0[4] = {va0[r].x, va0[r].y, va0[r].z, va0[r].w};
      float a1[4] = {va1[r].x, va1[r].y, va1[r].z, va1[r].w};
#pragma unroll
      for (int j = 0; j < 4; ++j) {
        unsigned pk = (unsigned)f2bf(a0[j]) | ((unsigned)f2bf(a1[j]) << 16);
        *reinterpret_cast<unsigned*>(&Ac[(sp4[r] + j) * 106 + 2 * sic[r]]) = pk;
      }
    }
    // issue next tile's loads (regs free again; covered by MFMA+epilogue)
    if (i < 3) {
      int p0n = p0 + 128;
#pragma unroll
      for (int r = 0; r < 6; ++r) {
        va0[r] = *reinterpret_cast<const float4*>(xb + (size_t)(2 * sic[r]) * HWC + p0n + sp4[r]);
        va1[r] = *reinterpret_cast<const float4*>(xb + (size_t)(2 * sic[r] + 1) * HWC + p0n + sp4[r]);
      }
    }
    __syncthreads();

    // MFMA
    f32x4 acc[4][3];
#pragma unroll
    for (int mt = 0; mt < 4; ++mt)
#pragma unroll
      for (int nt = 0; nt < 3; ++nt) acc[mt][nt] = (f32x4){0.f, 0.f, 0.f, 0.f};
#pragma unroll
    for (int kk = 0; kk < 3; ++kk) {
      bf16x8 a[4];
#pragma unroll
      for (int mt = 0; mt < 4; ++mt)
        a[mt] = *reinterpret_cast<const bf16x8*>(
            &Ac[(wm * 64 + mt * 16 + row) * 106 + kk * 32 + kg * 8]);
#pragma unroll
      for (int mt = 0; mt < 4; ++mt)
#pragma unroll
        for (int nt = 0; nt < 3; ++nt)
          acc[mt][nt] = __builtin_amdgcn_mfma_f32_16x16x32_bf16(
              a[mt], bfr[kk][nt], acc[mt][nt], 0, 0, 0);
    }
    __syncthreads();   // all frag reads of Ac done

    // epilogue: bias + bf16 -> tD (aliases Ac) -> coalesced stores
    unsigned short* tD = Ac;
#pragma unroll
    for (int nt = 0; nt < 3; ++nt) {
      int ocl = wn * 48 + nt * 16 + row;
      float bv = bias[nt];
#pragma unroll
      for (int mt = 0; mt < 4; ++mt) {
        int pxl = wm * 64 + mt * 16 + kg * 4;
        f32x4 v = acc[mt][nt];
        unsigned pk0 = (unsigned)f2bf(v[0] + bv) | ((unsigned)f2bf(v[1] + bv) << 16);
        unsigned pk1 = (unsigned)f2bf(v[2] + bv) | ((unsigned)f2bf(v[3] + bv) << 16);
        *reinterpret_cast<unsigned*>(&tD[ocl * 136 + pxl]) = pk0;
        *reinterpret_cast<unsigned*>(&tD[ocl * 136 + pxl + 2]) = pk1;
      }
    }
    __syncthreads();
    unsigned short* preb = pre + ((size_t)bz * C3 + o0) * HWC + p0;
#pragma unroll
    for (int r = 0; r < 6; ++r) {
      int lin = r * 256 + t;
      int oc = lin >> 4, ch = lin & 15;
      us8v v = *reinterpret_cast<const us8v*>(&tD[oc * 136 + ch * 8]);
      *reinterpret_cast<us8v*>(preb + (size_t)oc * HWC + ch * 8) = v;
    }
    p0 += 128;
  }
}

// K2: depthwise 3x3 + bias, 288 ch bf16. Tile 32x256. grid (288, 8, bc).
__global__ __launch_bounds__(256) void k2_dw(
    const unsigned short* __restrict__ pre, const float* __restrict__ dww,
    const float* __restrict__ dwb, unsigned short* __restrict__ dwo)
{
  __shared__ float s[34 * 268];
  const int t = threadIdx.x;
  const int c3 = blockIdx.x;
  const int h0 = blockIdx.y * 32;
  const int bz = blockIdx.z;
  const size_t choff = ((size_t)bz * C3 + c3) * HWC;
  const int rt = t >> 6, col4 = (t & 63) * 4;

  ushort4 uu[9];
#pragma unroll
  for (int r = 0; r < 9; ++r) {
    int row = r * 4 + rt;
    int hh = h0 + row - 1;
    uu[r] = make_ushort4(0, 0, 0, 0);
    if (row < 34 && hh >= 0 && hh < HH)
      uu[r] = *reinterpret_cast<const ushort4*>(pre + choff + hh * WW + col4);
  }
  __builtin_amdgcn_sched_barrier(0);
#pragma unroll
  for (int r = 0; r < 9; ++r) {
    int row = r * 4 + rt;
    if (row < 34) {
      *reinterpret_cast<float4*>(&s[row * 268 + 4 + col4]) =
          make_float4(bf2f(uu[r].x), bf2f(uu[r].y), bf2f(uu[r].z), bf2f(uu[r].w));
    }
  }
  if (t < 34) { s[t * 268 + 3] = 0.f; s[t * 268 + 260] = 0.f; }
  __syncthreads();

  float wg[9];
#pragma unroll
  for (int i = 0; i < 9; ++i) wg[i] = dww[c3 * 9 + i];
  const float bias = dwb[c3];

#pragma unroll
  for (int rr = 0; rr < 8; ++rr) {
    int orow = rr * 4 + rt;
    float a0 = bias, a1 = bias, a2 = bias, a3 = bias;
#pragma unroll
    for (int dy = 0; dy < 3; ++dy) {
      const float* rowp = &s[(orow + dy) * 268 + 4 + col4];
      float4 rA = *reinterpret_cast<const float4*>(rowp - 4);
      float4 rB = *reinterpret_cast<const float4*>(rowp);
      float4 rC = *reinterpret_cast<const float4*>(rowp + 4);
      float w0 = wg[dy * 3 + 0], w1 = wg[dy * 3 + 1], w2 = wg[dy * 3 + 2];
      a0 = fmaf(rA.w, w0, fmaf(rB.x, w1, fmaf(rB.y, w2, a0)));
      a1 = fmaf(rB.x, w0, fmaf(rB.y, w1, fmaf(rB.z, w2, a1)));
      a2 = fmaf(rB.y, w0, fmaf(rB.z, w1, fmaf(rB.w, w2, a2)));
      a3 = fmaf(rB.z, w0, fmaf(rB.w, w1, fmaf(rC.x, w2, a3)));
    }
    ushort4 u;
    u.x = f2bf(a0); u.y = f2bf(a1); u.z = f2bf(a2); u.w = f2bf(a3);
    *reinterpret_cast<ushort4*>((unsigned short*)dwo + choff + (h0 + orow) * WW + col4) = u;
  }
}

// K3: partial Gram per (c, head, b) from bf16 q,k; + sumsq via atomics.
__global__ __launch_bounds__(256) void k3_gram(
    const unsigned short* __restrict__ dwo, float* __restrict__ gpart,
    float* __restrict__ ssq)
{
  __shared__ float qs[256 * 32];
  __shared__ float ks[256 * 32];
  const int t = threadIdx.x;
  const int c = blockIdx.x, head = blockIdx.y, bz = blockIdx.z;
  const unsigned short* qp = dwo + ((size_t)bz * C3 + c) * HWC + head * W2;
  const unsigned short* kp = dwo + ((size_t)bz * C3 + CC + c) * HWC + head * W2;
  ushort4 qu[8], ku[8];
#pragma unroll
  for (int it = 0; it < 8; ++it) {
    int lin = it * 256 + t;
    int h = lin >> 3, j4 = (lin & 7) * 4;
    qu[it] = *reinterpret_cast<const ushort4*>(qp + h * WW + j4);
    ku[it] = *reinterpret_cast<const ushort4*>(kp + h * WW + j4);
  }
  __builtin_amdgcn_sched_barrier(0);
#pragma unroll
  for (int it = 0; it < 8; ++it) {
    int lin = it * 256 + t;
    int h = lin >> 3, j4 = (lin & 7) * 4;
    *reinterpret_cast<float4*>(&qs[h * 32 + j4]) =
        make_float4(bf2f(qu[it].x), bf2f(qu[it].y), bf2f(qu[it].z), bf2f(qu[it].w));
    *reinterpret_cast<float4*>(&ks[h * 32 + j4]) =
        make_float4(bf2f(ku[it].x), bf2f(ku[it].y), bf2f(ku[it].z), bf2f(ku[it].w));
  }
  __syncthreads();
  const int i = t & 31, jg = t >> 5;
  float a0 = 0, a1 = 0, a2 = 0, a3 = 0;
  for (int h = 0; h < 256; ++h) {
    float qv = qs[h * 32 + i];
    float4 kv = *reinterpret_cast<const float4*>(&ks[h * 32 + jg * 4]);
    a0 = fmaf(qv, kv.x, a0); a1 = fmaf(qv, kv.y, a1);
    a2 = fmaf(qv, kv.z, a2); a3 = fmaf(qv, kv.w, a3);
  }
  float* gp = gpart + (((size_t)bz * NHEADS + head) * CC + c) * 1024;
  gp[(jg * 4 + 0) * 32 + i] = a0;
  gp[(jg * 4 + 1) * 32 + i] = a1;
  gp[(jg * 4 + 2) * 32 + i] = a2;
  gp[(jg * 4 + 3) * 32 + i] = a3;
  if (t < 64) {
    const float* src = (t < 32) ? qs : ks;
    const int col = t & 31;
    float ssum = 0;
    for (int h = 0; h < 256; ++h) { float v = src[h * 32 + col]; ssum = fmaf(v, v, ssum); }
    atomicAdd(&ssq[((size_t)bz * 2 + (t >> 5)) * 256 + head * W2 + col], ssum);
  }
}

// K4a: reduce gpart over c -> g[b,h,1024]. grid (8, 8, bc), block 256.
__global__ __launch_bounds__(256) void k4a_reduce(
    const float* __restrict__ gpart, float* __restrict__ g)
{
  __shared__ float l[256];
  const int t = threadIdx.x;
  const int head = blockIdx.x, chunk = blockIdx.y, bz = blockIdx.z;
  const int e = chunk * 128 + (t & 127);
  const int half = t >> 7;
  const float* gp = gpart + (((size_t)bz * NHEADS + head) * CC + half * 48) * 1024 + e;
  float s = 0.f;
#pragma unroll 4
  for (int c = 0; c < 48; ++c) s += gp[(size_t)c * 1024];
  l[t] = s;
  __syncthreads();
  if (t < 128)
    g[((size_t)bz * NHEADS + head) * 1024 + chunk * 128 + t] = l[t] + l[t + 128];
}

// K4b: normalize + temperature + softmax. grid (8, bc), block 64.
__global__ __launch_bounds__(64) void k4b_softmax(
    const float* __restrict__ g, const float* __restrict__ ssq,
    const float* __restrict__ temp, float* __restrict__ attn)
{
  const int t = threadIdx.x;
  const int head = blockIdx.x, bz = blockIdx.y;
  if (t >= 32) return;
  const int i = t;
  const float* gb = g + ((size_t)bz * NHEADS + head) * 1024;
  const float* sq_ = ssq + (size_t)bz * 512 + head * W2;
  const float* sk_ = ssq + (size_t)bz * 512 + 256 + head * W2;
  float invq = 1.f / fmaxf(sqrtf(sq_[i]), 1e-12f);
  float tpq = temp[head] * invq;
  float row[32];
  float m = -1e30f;
#pragma unroll
  for (int j = 0; j < 32; ++j) {
    float invk = 1.f / fmaxf(sqrtf(sk_[j]), 1e-12f);
    float v = gb[j * 32 + i] * tpq * invk;
    row[j] = v;
    m = fmaxf(m, v);
  }
  float ssum = 0;
#pragma unroll
  for (int j = 0; j < 32; ++j) { row[j] = expf(row[j] - m); ssum += row[j]; }
  float inv = 1.f / ssum;
  float* ap = attn + ((size_t)bz * NHEADS + head) * 1024 + i * 32;
#pragma unroll
  for (int j = 0; j < 32; ++j) ap[j] = row[j] * inv;
}

// K5a: t = attn @ v via MFMA. grid (384, bc), block 256 (4 waves).
__global__ __launch_bounds__(256) void k5a_attnv(
    const unsigned short* __restrict__ dwo, const float* __restrict__ attn,
    unsigned short* __restrict__ tbuf)
{
  __shared__ __align__(16) unsigned short vsm[64 * 264];     // v tile / tD reuse
  __shared__ __align__(16) unsigned short atn_s[256 * 36];   // attn bf16, pitch 36
  const int t = threadIdx.x;
  const int tile = blockIdx.x;
  const int bz = blockIdx.y;
  const size_t R0 = (size_t)tile * 64;
  const unsigned short* vsrc = dwo + ((size_t)bz * C3 + 2 * CC) * HWC + R0 * 256;

  us8v vv[8];
#pragma unroll
  for (int j = 0; j < 8; ++j)
    vv[j] = *reinterpret_cast<const us8v*>(vsrc + (size_t)(j * 256 + t) * 8);
  float4 av[8];
  {
    const float* ap = attn + (size_t)bz * 8192 + t * 32;
#pragma unroll
    for (int k = 0; k < 8; ++k)
      av[k] = *reinterpret_cast<const float4*>(ap + k * 4);
  }
  __builtin_amdgcn_sched_barrier(0);
#pragma unroll
  for (int j = 0; j < 8; ++j) {
    int n = j * 256 + t;
    int row = n >> 5, c8 = n & 31;
    *reinterpret_cast<us8v*>(&vsm[row * 264 + c8 * 8]) = vv[j];
  }
#pragma unroll
  for (int k = 0; k < 8; ++k) {
    ushort4 u;
    u.x = f2bf(av[k].x); u.y = f2bf(av[k].y); u.z = f2bf(av[k].z); u.w = f2bf(av[k].w);
    *reinterpret_cast<ushort4*>(&atn_s[t * 36 + k * 4]) = u;
  }
  __syncthreads();

  const int wave = t >> 6, lane = t & 63;
  const int mrow = lane & 15, kg = lane >> 4;

  bf16x8 a[8], b[16];
#pragma unroll
  for (int hd = 0; hd < 8; ++hd)
    a[hd] = *reinterpret_cast<const bf16x8*>(
        &vsm[(wave * 16 + mrow) * 264 + hd * 32 + kg * 8]);
#pragma unroll
  for (int hd = 0; hd < 8; ++hd)
#pragma unroll
    for (int it = 0; it < 2; ++it)
      b[hd * 2 + it] = *reinterpret_cast<const bf16x8*>(
          &atn_s[(hd * 32 + it * 16 + mrow) * 36 + kg * 8]);

  f32x4 acc[16];
#pragma unroll
  for (int q = 0; q < 16; ++q) acc[q] = (f32x4){0.f, 0.f, 0.f, 0.f};
#pragma unroll
  for (int hd = 0; hd < 8; ++hd)
#pragma unroll
    for (int it = 0; it < 2; ++it)
      acc[hd * 2 + it] = __builtin_amdgcn_mfma_f32_16x16x32_bf16(
          a[hd], b[hd * 2 + it], acc[hd * 2 + it], 0, 0, 0);
  __syncthreads();   // all v reads done; reuse vsm as tD

#pragma unroll
  for (int hd = 0; hd < 8; ++hd)
#pragma unroll
    for (int it = 0; it < 2; ++it) {
      f32x4 v = acc[hd * 2 + it];
      int col = hd * 32 + it * 16 + mrow;
#pragma unroll
      for (int r = 0; r < 4; ++r)
        vsm[(wave * 16 + kg * 4 + r) * 264 + col] = f2bf(v[r]);
    }
  unsigned short* tdst = tbuf + (size_t)bz * CC * HWC + R0 * 256;
#pragma unroll
  for (int k = 0; k < 8; ++k) {
    int n = k * 64 + lane;
    int rloc = n >> 5, c8 = n & 31;
    us8v v = *reinterpret_cast<const us8v*>(&vsm[(wave * 16 + rloc) * 264 + c8 * 8]);
    *reinterpret_cast<us8v*>(tdst + ((size_t)(wave * 16 + rloc)) * 256 + c8 * 8) = v;
  }
}

// K5b: out = proj(t) + pb via MFMA. grid (512, bc), block 256.
__global__ __launch_bounds__(256) void k5b_proj(
    const unsigned short* __restrict__ tbuf, const float* __restrict__ pw,
    const float* __restrict__ pb, float* __restrict__ out, int b0)
{
  __shared__ __align__(16) char smem[50688];
  unsigned short* As = (unsigned short*)smem;            // [128][106]
  unsigned short* Ws = (unsigned short*)(smem + 27136);  // [96][106]
  float* tD = (float*)smem;                               // [96][132] (reuse)
  const int t = threadIdx.x;
  const int p0 = blockIdx.x * 128;
  const int bz = blockIdx.y;
  const unsigned short* tb = tbuf + (size_t)bz * CC * HWC;

  us8v ua0[3], ua1[3];
#pragma unroll
  for (int r = 0; r < 3; ++r) {
    int lin = r * 256 + t;
    int icp = lin >> 4, p8 = (lin & 15) * 8;
    ua0[r] = *reinterpret_cast<const us8v*>(tb + (size_t)(2 * icp) * HWC + p0 + p8);
    ua1[r] = *reinterpret_cast<const us8v*>(tb + (size_t)(2 * icp + 1) * HWC + p0 + p8);
  }
  float4 vw[9];
#pragma unroll
  for (int r = 0; r < 9; ++r) {
    int lin = r * 256 + t;
    int oc = lin / 24;
    int ic4 = (lin - oc * 24) * 4;
    vw[r] = *reinterpret_cast<const float4*>(pw + (size_t)oc * 96 + ic4);
  }
  __builtin_amdgcn_sched_barrier(0);
#pragma unroll
  for (int r = 0; r < 3; ++r) {
    int lin = r * 256 + t;
    int icp = lin >> 4, p8 = (lin & 15) * 8;
#pragma unroll
    for (int j = 0; j < 8; ++j) {
      unsigned pk = (unsigned)ua0[r][j] | ((unsigned)ua1[r][j] << 16);
      *reinterpret_cast<unsigned*>(&As[(p8 + j) * 106 + 2 * icp]) = pk;
    }
  }
#pragma unroll
  for (int r = 0; r < 9; ++r) {
    int lin = r * 256 + t;
    int oc = lin / 24;
    int ic4 = (lin - oc * 24) * 4;
    ushort4 u;
    u.x = f2bf(vw[r].x); u.y = f2bf(vw[r].y); u.z = f2bf(vw[r].z); u.w = f2bf(vw[r].w);
    *reinterpret_cast<ushort4*>(&Ws[oc * 106 + ic4]) = u;
  }
  __syncthreads();

  const int wave = t >> 6, lane = t & 63;
  const int wm = wave & 1, wn = wave >> 1;
  const int row = lane & 15, kg = lane >> 4;

  f32x4 acc[4][3];
#pragma unroll
  for (int mt = 0; mt < 4; ++mt)
#pragma unroll
    for (int nt = 0; nt < 3; ++nt) acc[mt][nt] = (f32x4){0.f, 0.f, 0.f, 0.f};

#pragma unroll
  for (int kk = 0; kk < 3; ++kk) {
    bf16x8 a[4], b[3];
#pragma unroll
    for (int mt = 0; mt < 4; ++mt)
      a[mt] = *reinterpret_cast<const bf16x8*>(
          &As[(wm * 64 + mt * 16 + row) * 106 + kk * 32 + kg * 8]);
#pragma unroll
    for (int nt = 0; nt < 3; ++nt)
      b[nt] = *reinterpret_cast<const bf16x8*>(
          &Ws[(wn * 48 + nt * 16 + row) * 106 + kk * 32 + kg * 8]);
#pragma unroll
    for (int mt = 0; mt < 4; ++mt)
#pragma unroll
      for (int nt = 0; nt < 3; ++nt)
        acc[mt][nt] = __builtin_amdgcn_mfma_f32_16x16x32_bf16(
            a[mt], b[nt], acc[mt][nt], 0, 0, 0);
  }
  __syncthreads();   // reuse LDS as tD fp32 [o][p]

#pragma unroll
  for (int nt = 0; nt < 3; ++nt) {
    int ocl = wn * 48 + nt * 16 + row;
    float bv = pb[ocl];
#pragma unroll
    for (int mt = 0; mt < 4; ++mt) {
      int pxl = wm * 64 + mt * 16 + kg * 4;
      f32x4 v = acc[mt][nt];
      float4 w = make_float4(v[0] + bv, v[1] + bv, v[2] + bv, v[3] + bv);
      *reinterpret_cast<float4*>(&tD[ocl * 132 + pxl]) = w;
    }
  }
  __syncthreads();
  float* ob = out + (size_t)(b0 + bz) * CC * HWC + p0;
#pragma unroll
  for (int r = 0; r < 12; ++r) {
    int lin = r * 256 + t;
    int o = lin >> 5, p4 = (lin & 31) * 4;
    float4 v = *reinterpret_cast<const float4*>(&tD[o * 132 + p4]);
    *reinterpret_cast<float4*>(ob + (size_t)o * HWC + p4) = v;
  }
}

extern "C" void kernel_launch(void* const* d_in, const int* in_sizes, int n_in,
                              void* d_out, int out_size, void* d_ws, size_t ws_size,
                              hipStream_t stream)
{
  const float* x      = (const float*)d_in[0];
  const float* qkv_w  = (const float*)d_in[1];
  const float* qkv_b  = (const float*)d_in[2];
  const float* dw_w   = (const float*)d_in[3];
  const float* dw_b   = (const float*)d_in[4];
  const float* proj_w = (const float*)d_in[5];
  const float* proj_b = (const float*)d_in[6];
  const float* temp   = (const float*)d_in[7];
  float* out = (float*)d_out;

  const size_t per_pre  = (size_t)C3 * HWC * 2;             // bf16, 37.7 MB
  const size_t per_gp   = (size_t)NHEADS * CC * 1024 * 4;   // 3.1 MB
  const size_t per_ssq  = (size_t)2 * 256 * 4;
  const size_t per_attn = (size_t)NHEADS * 1024 * 4;
  const size_t per_g    = (size_t)NHEADS * 1024 * 4;
  const size_t per_b = per_pre * 2 + per_gp + per_ssq + per_attn + per_g;

  int bc = 4;
  while (bc > 1 && per_b * (size_t)bc > ws_size) bc >>= 1;

  char* p = (char*)d_ws;
  unsigned short* pre = (unsigned short*)p; p += per_pre * bc;
  unsigned short* dwo = (unsigned short*)p; p += per_pre * bc;
  float* gpart = (float*)p; p += per_gp * bc;
  float* ssq   = (float*)p; p += per_ssq * bc;
  float* attn  = (float*)p; p += per_attn * bc;
  float* g     = (float*)p; p += per_g * bc;
  unsigned short* tbuf = pre;   // pre dead after k2

  for (int b0 = 0; b0 < 4; b0 += bc) {
    k1_qkv_mfma<<<dim3(128, 3, bc), 256, 0, stream>>>(x, qkv_w, qkv_b, pre, b0);
    k2_dw<<<dim3(C3, 8, bc), 256, 0, stream>>>(pre, dw_w, dw_b, dwo);
    hipMemsetAsync(ssq, 0, per_ssq * bc, stream);
    k3_gram<<<dim3(CC, NHEADS, bc), 256, 0, stream>>>(dwo, gpart, ssq);
    k4a_reduce<<<dim3(NHEADS, 8, bc), 256, 0, stream>>>(gpart, g);
    k4b_softmax<<<dim3(NHEADS, bc), 64, 0, stream>>>(g, ssq, temp, attn);
    k5a_attnv<<<dim3(384, bc), 256, 0, stream>>>(dwo, attn, tbuf);
    k5b_proj<<<dim3(512, bc), 256, 0, stream>>>(tbuf, proj_w, proj_b, out, b0);
  }
}

// Round 7
// 269.779 us; speedup vs baseline: 2.9262x; 1.1039x over previous
//
#include <hip/hip_runtime.h>

#define CC 96
#define C3 288
#define HH 256
#define WW 256
#define HWC 65536
#define NHEADS 8
#define W2 32

typedef __bf16 bf16x8 __attribute__((ext_vector_type(8)));
typedef float f32x4 __attribute__((ext_vector_type(4)));
typedef unsigned short us8v __attribute__((ext_vector_type(8)));

__device__ __forceinline__ float bf2f(unsigned short u) {
  return __uint_as_float(((unsigned)u) << 16);
}
__device__ __forceinline__ unsigned short f2bf(float f) {
  unsigned u = __float_as_uint(f);
  unsigned r = u + 0x7fffu + ((u >> 16) & 1u);
  return (unsigned short)(r >> 16);
}

// K1 v3: qkv conv1x1 via bf16 MFMA, software-pipelined over 4 px-tiles/block.
__global__ __launch_bounds__(256, 2) void k1_qkv_mfma(
    const float* __restrict__ x, const float* __restrict__ qw,
    const float* __restrict__ qb, unsigned short* __restrict__ pre, int b0)
{
  __shared__ __align__(16) unsigned short As2[2][128 * 106];
  const int t = threadIdx.x;
  const int o0 = blockIdx.y * 96;
  const int bz = blockIdx.z;
  const float* xb = x + (size_t)(b0 + bz) * CC * HWC;

  const int wave = t >> 6, lane = t & 63;
  const int wm = wave & 1, wn = wave >> 1;
  const int row = lane & 15, kg = lane >> 4;

  bf16x8 bfr[3][3];
  float bias[3];
#pragma unroll
  for (int nt = 0; nt < 3; ++nt) {
    int ocl = wn * 48 + nt * 16 + row;
    bias[nt] = qb[o0 + ocl];
#pragma unroll
    for (int kk = 0; kk < 3; ++kk) {
      const float* wp = qw + (size_t)(o0 + ocl) * 96 + kk * 32 + kg * 8;
      float4 w0 = *reinterpret_cast<const float4*>(wp);
      float4 w1 = *reinterpret_cast<const float4*>(wp + 4);
      us8v u;
      u[0] = f2bf(w0.x); u[1] = f2bf(w0.y); u[2] = f2bf(w0.z); u[3] = f2bf(w0.w);
      u[4] = f2bf(w1.x); u[5] = f2bf(w1.y); u[6] = f2bf(w1.z); u[7] = f2bf(w1.w);
      bfr[kk][nt] = *reinterpret_cast<bf16x8*>(&u);
    }
  }

  int sic[6], sp4[6];
#pragma unroll
  for (int r = 0; r < 6; ++r) {
    int lin = r * 256 + t;
    sic[r] = lin >> 5;
    sp4[r] = (lin & 31) * 4;
  }

  int p0 = blockIdx.x * 512;
  float4 va0[6], va1[6];
#pragma unroll
  for (int r = 0; r < 6; ++r) {
    va0[r] = *reinterpret_cast<const float4*>(xb + (size_t)(2 * sic[r]) * HWC + p0 + sp4[r]);
    va1[r] = *reinterpret_cast<const float4*>(xb + (size_t)(2 * sic[r] + 1) * HWC + p0 + sp4[r]);
  }

  for (int i = 0; i < 4; ++i) {
    unsigned short* Ac = As2[i & 1];
#pragma unroll
    for (int r = 0; r < 6; ++r) {
      float a0[4] = {va0[r].x, va0[r].y, va0[r].z, va0[r].w};
      float a1[4] = {va1[r].x, va1[r].y, va1[r].z, va1[r].w};
#pragma unroll
      for (int j = 0; j < 4; ++j) {
        unsigned pk = (unsigned)f2bf(a0[j]) | ((unsigned)f2bf(a1[j]) << 16);
        *reinterpret_cast<unsigned*>(&Ac[(sp4[r] + j) * 106 + 2 * sic[r]]) = pk;
      }
    }
    if (i < 3) {
      int p0n = p0 + 128;
#pragma unroll
      for (int r = 0; r < 6; ++r) {
        va0[r] = *reinterpret_cast<const float4*>(xb + (size_t)(2 * sic[r]) * HWC + p0n + sp4[r]);
        va1[r] = *reinterpret_cast<const float4*>(xb + (size_t)(2 * sic[r] + 1) * HWC + p0n + sp4[r]);
      }
    }
    __syncthreads();

    f32x4 acc[4][3];
#pragma unroll
    for (int mt = 0; mt < 4; ++mt)
#pragma unroll
      for (int nt = 0; nt < 3; ++nt) acc[mt][nt] = (f32x4){0.f, 0.f, 0.f, 0.f};
#pragma unroll
    for (int kk = 0; kk < 3; ++kk) {
      bf16x8 a[4];
#pragma unroll
      for (int mt = 0; mt < 4; ++mt)
        a[mt] = *reinterpret_cast<const bf16x8*>(
            &Ac[(wm * 64 + mt * 16 + row) * 106 + kk * 32 + kg * 8]);
#pragma unroll
      for (int mt = 0; mt < 4; ++mt)
#pragma unroll
        for (int nt = 0; nt < 3; ++nt)
          acc[mt][nt] = __builtin_amdgcn_mfma_f32_16x16x32_bf16(
              a[mt], bfr[kk][nt], acc[mt][nt], 0, 0, 0);
    }
    __syncthreads();

    unsigned short* tD = Ac;
#pragma unroll
    for (int nt = 0; nt < 3; ++nt) {
      int ocl = wn * 48 + nt * 16 + row;
      float bv = bias[nt];
#pragma unroll
      for (int mt = 0; mt < 4; ++mt) {
        int pxl = wm * 64 + mt * 16 + kg * 4;
        f32x4 v = acc[mt][nt];
        unsigned pk0 = (unsigned)f2bf(v[0] + bv) | ((unsigned)f2bf(v[1] + bv) << 16);
        unsigned pk1 = (unsigned)f2bf(v[2] + bv) | ((unsigned)f2bf(v[3] + bv) << 16);
        *reinterpret_cast<unsigned*>(&tD[ocl * 136 + pxl]) = pk0;
        *reinterpret_cast<unsigned*>(&tD[ocl * 136 + pxl + 2]) = pk1;
      }
    }
    __syncthreads();
    unsigned short* preb = pre + ((size_t)bz * C3 + o0) * HWC + p0;
#pragma unroll
    for (int r = 0; r < 6; ++r) {
      int lin = r * 256 + t;
      int oc = lin >> 4, ch = lin & 15;
      us8v v = *reinterpret_cast<const us8v*>(&tD[oc * 136 + ch * 8]);
      *reinterpret_cast<us8v*>(preb + (size_t)oc * HWC + ch * 8) = v;
    }
    p0 += 128;
  }
}

// K2 v2: depthwise 3x3 + bias, LDS-free register-rolling.
// grid (288, 8, bc), block 256 = 8 teams x 32 lanes. Team owns 4 output rows,
// lane owns 8 px. 6 input rows in float8 regs; horizontal halo via shfl.
__global__ __launch_bounds__(256) void k2_dw(
    const unsigned short* __restrict__ pre, const float* __restrict__ dww,
    const float* __restrict__ dwb, unsigned short* __restrict__ dwo)
{
  const int t = threadIdx.x;
  const int c3 = blockIdx.x;
  const int hb = blockIdx.y;
  const int bz = blockIdx.z;
  const size_t choff = ((size_t)bz * C3 + c3) * HWC;
  const int team = t >> 5, tl = t & 31;
  const int h0 = hb * 32 + team * 4;

  // issue all 6 row loads first (coalesced 16B/lane)
  us8v rin[6];
#pragma unroll
  for (int r = 0; r < 6; ++r) {
    int hh = h0 - 1 + r;
    if (hh >= 0 && hh < HH)
      rin[r] = *reinterpret_cast<const us8v*>(pre + choff + (size_t)hh * WW + tl * 8);
    else
      rin[r] = (us8v){0, 0, 0, 0, 0, 0, 0, 0};
  }

  float wg[9];
#pragma unroll
  for (int i = 0; i < 9; ++i) wg[i] = dww[c3 * 9 + i];
  const float bias = dwb[c3];

  // convert + edge exchange
  float f[6][8];
  float lf[6], rt[6];
#pragma unroll
  for (int r = 0; r < 6; ++r) {
#pragma unroll
    for (int j = 0; j < 8; ++j) f[r][j] = bf2f(rin[r][j]);
    float l = __shfl_up(f[r][7], 1, 32);
    float rr = __shfl_down(f[r][0], 1, 32);
    lf[r] = (tl == 0) ? 0.f : l;
    rt[r] = (tl == 31) ? 0.f : rr;
  }

#pragma unroll
  for (int orow = 0; orow < 4; ++orow) {
    float o[8];
#pragma unroll
    for (int j = 0; j < 8; ++j) o[j] = bias;
#pragma unroll
    for (int k = 0; k < 3; ++k) {
      const int r = orow + k;
      const float w0 = wg[k * 3 + 0], w1 = wg[k * 3 + 1], w2 = wg[k * 3 + 2];
      o[0] = fmaf(lf[r], w0, fmaf(f[r][0], w1, fmaf(f[r][1], w2, o[0])));
#pragma unroll
      for (int j = 1; j < 7; ++j)
        o[j] = fmaf(f[r][j - 1], w0, fmaf(f[r][j], w1, fmaf(f[r][j + 1], w2, o[j])));
      o[7] = fmaf(f[r][6], w0, fmaf(f[r][7], w1, fmaf(rt[r], w2, o[7])));
    }
    us8v u;
#pragma unroll
    for (int j = 0; j < 8; ++j) u[j] = f2bf(o[j]);
    *reinterpret_cast<us8v*>((unsigned short*)dwo + choff + (size_t)(h0 + orow) * WW + tl * 8) = u;
  }
}

// K3: partial Gram per (c, head, b) from bf16 q,k; + sumsq via atomics.
__global__ __launch_bounds__(256) void k3_gram(
    const unsigned short* __restrict__ dwo, float* __restrict__ gpart,
    float* __restrict__ ssq)
{
  __shared__ float qs[256 * 32];
  __shared__ float ks[256 * 32];
  const int t = threadIdx.x;
  const int c = blockIdx.x, head = blockIdx.y, bz = blockIdx.z;
  const unsigned short* qp = dwo + ((size_t)bz * C3 + c) * HWC + head * W2;
  const unsigned short* kp = dwo + ((size_t)bz * C3 + CC + c) * HWC + head * W2;
  ushort4 qu[8], ku[8];
#pragma unroll
  for (int it = 0; it < 8; ++it) {
    int lin = it * 256 + t;
    int h = lin >> 3, j4 = (lin & 7) * 4;
    qu[it] = *reinterpret_cast<const ushort4*>(qp + h * WW + j4);
    ku[it] = *reinterpret_cast<const ushort4*>(kp + h * WW + j4);
  }
  __builtin_amdgcn_sched_barrier(0);
#pragma unroll
  for (int it = 0; it < 8; ++it) {
    int lin = it * 256 + t;
    int h = lin >> 3, j4 = (lin & 7) * 4;
    *reinterpret_cast<float4*>(&qs[h * 32 + j4]) =
        make_float4(bf2f(qu[it].x), bf2f(qu[it].y), bf2f(qu[it].z), bf2f(qu[it].w));
    *reinterpret_cast<float4*>(&ks[h * 32 + j4]) =
        make_float4(bf2f(ku[it].x), bf2f(ku[it].y), bf2f(ku[it].z), bf2f(ku[it].w));
  }
  __syncthreads();
  const int i = t & 31, jg = t >> 5;
  float a0 = 0, a1 = 0, a2 = 0, a3 = 0;
  for (int h = 0; h < 256; ++h) {
    float qv = qs[h * 32 + i];
    float4 kv = *reinterpret_cast<const float4*>(&ks[h * 32 + jg * 4]);
    a0 = fmaf(qv, kv.x, a0); a1 = fmaf(qv, kv.y, a1);
    a2 = fmaf(qv, kv.z, a2); a3 = fmaf(qv, kv.w, a3);
  }
  float* gp = gpart + (((size_t)bz * NHEADS + head) * CC + c) * 1024;
  gp[(jg * 4 + 0) * 32 + i] = a0;
  gp[(jg * 4 + 1) * 32 + i] = a1;
  gp[(jg * 4 + 2) * 32 + i] = a2;
  gp[(jg * 4 + 3) * 32 + i] = a3;
  if (t < 64) {
    const float* src = (t < 32) ? qs : ks;
    const int col = t & 31;
    float ssum = 0;
    for (int h = 0; h < 256; ++h) { float v = src[h * 32 + col]; ssum = fmaf(v, v, ssum); }
    atomicAdd(&ssq[((size_t)bz * 2 + (t >> 5)) * 256 + head * W2 + col], ssum);
  }
}

// K4a: reduce gpart over c -> g[b,h,1024]. grid (8, 8, bc), block 256.
__global__ __launch_bounds__(256) void k4a_reduce(
    const float* __restrict__ gpart, float* __restrict__ g)
{
  __shared__ float l[256];
  const int t = threadIdx.x;
  const int head = blockIdx.x, chunk = blockIdx.y, bz = blockIdx.z;
  const int e = chunk * 128 + (t & 127);
  const int half = t >> 7;
  const float* gp = gpart + (((size_t)bz * NHEADS + head) * CC + half * 48) * 1024 + e;
  float s = 0.f;
#pragma unroll 4
  for (int c = 0; c < 48; ++c) s += gp[(size_t)c * 1024];
  l[t] = s;
  __syncthreads();
  if (t < 128)
    g[((size_t)bz * NHEADS + head) * 1024 + chunk * 128 + t] = l[t] + l[t + 128];
}

// K4b: normalize + temperature + softmax. grid (8, bc), block 64.
__global__ __launch_bounds__(64) void k4b_softmax(
    const float* __restrict__ g, const float* __restrict__ ssq,
    const float* __restrict__ temp, float* __restrict__ attn)
{
  const int t = threadIdx.x;
  const int head = blockIdx.x, bz = blockIdx.y;
  if (t >= 32) return;
  const int i = t;
  const float* gb = g + ((size_t)bz * NHEADS + head) * 1024;
  const float* sq_ = ssq + (size_t)bz * 512 + head * W2;
  const float* sk_ = ssq + (size_t)bz * 512 + 256 + head * W2;
  float invq = 1.f / fmaxf(sqrtf(sq_[i]), 1e-12f);
  float tpq = temp[head] * invq;
  float row[32];
  float m = -1e30f;
#pragma unroll
  for (int j = 0; j < 32; ++j) {
    float invk = 1.f / fmaxf(sqrtf(sk_[j]), 1e-12f);
    float v = gb[j * 32 + i] * tpq * invk;
    row[j] = v;
    m = fmaxf(m, v);
  }
  float ssum = 0;
#pragma unroll
  for (int j = 0; j < 32; ++j) { row[j] = expf(row[j] - m); ssum += row[j]; }
  float inv = 1.f / ssum;
  float* ap = attn + ((size_t)bz * NHEADS + head) * 1024 + i * 32;
#pragma unroll
  for (int j = 0; j < 32; ++j) ap[j] = row[j] * inv;
}

// K5a: t = attn @ v via MFMA. grid (384, bc), block 256 (4 waves).
__global__ __launch_bounds__(256) void k5a_attnv(
    const unsigned short* __restrict__ dwo, const float* __restrict__ attn,
    unsigned short* __restrict__ tbuf)
{
  __shared__ __align__(16) unsigned short vsm[64 * 264];
  __shared__ __align__(16) unsigned short atn_s[256 * 36];
  const int t = threadIdx.x;
  const int tile = blockIdx.x;
  const int bz = blockIdx.y;
  const size_t R0 = (size_t)tile * 64;
  const unsigned short* vsrc = dwo + ((size_t)bz * C3 + 2 * CC) * HWC + R0 * 256;

  us8v vv[8];
#pragma unroll
  for (int j = 0; j < 8; ++j)
    vv[j] = *reinterpret_cast<const us8v*>(vsrc + (size_t)(j * 256 + t) * 8);
  float4 av[8];
  {
    const float* ap = attn + (size_t)bz * 8192 + t * 32;
#pragma unroll
    for (int k = 0; k < 8; ++k)
      av[k] = *reinterpret_cast<const float4*>(ap + k * 4);
  }
  __builtin_amdgcn_sched_barrier(0);
#pragma unroll
  for (int j = 0; j < 8; ++j) {
    int n = j * 256 + t;
    int row = n >> 5, c8 = n & 31;
    *reinterpret_cast<us8v*>(&vsm[row * 264 + c8 * 8]) = vv[j];
  }
#pragma unroll
  for (int k = 0; k < 8; ++k) {
    ushort4 u;
    u.x = f2bf(av[k].x); u.y = f2bf(av[k].y); u.z = f2bf(av[k].z); u.w = f2bf(av[k].w);
    *reinterpret_cast<ushort4*>(&atn_s[t * 36 + k * 4]) = u;
  }
  __syncthreads();

  const int wave = t >> 6, lane = t & 63;
  const int mrow = lane & 15, kg = lane >> 4;

  bf16x8 a[8], b[16];
#pragma unroll
  for (int hd = 0; hd < 8; ++hd)
    a[hd] = *reinterpret_cast<const bf16x8*>(
        &vsm[(wave * 16 + mrow) * 264 + hd * 32 + kg * 8]);
#pragma unroll
  for (int hd = 0; hd < 8; ++hd)
#pragma unroll
    for (int it = 0; it < 2; ++it)
      b[hd * 2 + it] = *reinterpret_cast<const bf16x8*>(
          &atn_s[(hd * 32 + it * 16 + mrow) * 36 + kg * 8]);

  f32x4 acc[16];
#pragma unroll
  for (int q = 0; q < 16; ++q) acc[q] = (f32x4){0.f, 0.f, 0.f, 0.f};
#pragma unroll
  for (int hd = 0; hd < 8; ++hd)
#pragma unroll
    for (int it = 0; it < 2; ++it)
      acc[hd * 2 + it] = __builtin_amdgcn_mfma_f32_16x16x32_bf16(
          a[hd], b[hd * 2 + it], acc[hd * 2 + it], 0, 0, 0);
  __syncthreads();

#pragma unroll
  for (int hd = 0; hd < 8; ++hd)
#pragma unroll
    for (int it = 0; it < 2; ++it) {
      f32x4 v = acc[hd * 2 + it];
      int col = hd * 32 + it * 16 + mrow;
#pragma unroll
      for (int r = 0; r < 4; ++r)
        vsm[(wave * 16 + kg * 4 + r) * 264 + col] = f2bf(v[r]);
    }
  unsigned short* tdst = tbuf + (size_t)bz * CC * HWC + R0 * 256;
#pragma unroll
  for (int k = 0; k < 8; ++k) {
    int n = k * 64 + lane;
    int rloc = n >> 5, c8 = n & 31;
    us8v v = *reinterpret_cast<const us8v*>(&vsm[(wave * 16 + rloc) * 264 + c8 * 8]);
    *reinterpret_cast<us8v*>(tdst + ((size_t)(wave * 16 + rloc)) * 256 + c8 * 8) = v;
  }
}

// K5b: out = proj(t) + pb via MFMA. grid (512, bc), block 256.
__global__ __launch_bounds__(256) void k5b_proj(
    const unsigned short* __restrict__ tbuf, const float* __restrict__ pw,
    const float* __restrict__ pb, float* __restrict__ out, int b0)
{
  __shared__ __align__(16) char smem[50688];
  unsigned short* As = (unsigned short*)smem;
  unsigned short* Ws = (unsigned short*)(smem + 27136);
  float* tD = (float*)smem;
  const int t = threadIdx.x;
  const int p0 = blockIdx.x * 128;
  const int bz = blockIdx.y;
  const unsigned short* tb = tbuf + (size_t)bz * CC * HWC;

  us8v ua0[3], ua1[3];
#pragma unroll
  for (int r = 0; r < 3; ++r) {
    int lin = r * 256 + t;
    int icp = lin >> 4, p8 = (lin & 15) * 8;
    ua0[r] = *reinterpret_cast<const us8v*>(tb + (size_t)(2 * icp) * HWC + p0 + p8);
    ua1[r] = *reinterpret_cast<const us8v*>(tb + (size_t)(2 * icp + 1) * HWC + p0 + p8);
  }
  float4 vw[9];
#pragma unroll
  for (int r = 0; r < 9; ++r) {
    int lin = r * 256 + t;
    int oc = lin / 24;
    int ic4 = (lin - oc * 24) * 4;
    vw[r] = *reinterpret_cast<const float4*>(pw + (size_t)oc * 96 + ic4);
  }
  __builtin_amdgcn_sched_barrier(0);
#pragma unroll
  for (int r = 0; r < 3; ++r) {
    int lin = r * 256 + t;
    int icp = lin >> 4, p8 = (lin & 15) * 8;
#pragma unroll
    for (int j = 0; j < 8; ++j) {
      unsigned pk = (unsigned)ua0[r][j] | ((unsigned)ua1[r][j] << 16);
      *reinterpret_cast<unsigned*>(&As[(p8 + j) * 106 + 2 * icp]) = pk;
    }
  }
#pragma unroll
  for (int r = 0; r < 9; ++r) {
    int lin = r * 256 + t;
    int oc = lin / 24;
    int ic4 = (lin - oc * 24) * 4;
    ushort4 u;
    u.x = f2bf(vw[r].x); u.y = f2bf(vw[r].y); u.z = f2bf(vw[r].z); u.w = f2bf(vw[r].w);
    *reinterpret_cast<ushort4*>(&Ws[oc * 106 + ic4]) = u;
  }
  __syncthreads();

  const int wave = t >> 6, lane = t & 63;
  const int wm = wave & 1, wn = wave >> 1;
  const int row = lane & 15, kg = lane >> 4;

  f32x4 acc[4][3];
#pragma unroll
  for (int mt = 0; mt < 4; ++mt)
#pragma unroll
    for (int nt = 0; nt < 3; ++nt) acc[mt][nt] = (f32x4){0.f, 0.f, 0.f, 0.f};

#pragma unroll
  for (int kk = 0; kk < 3; ++kk) {
    bf16x8 a[4], b[3];
#pragma unroll
    for (int mt = 0; mt < 4; ++mt)
      a[mt] = *reinterpret_cast<const bf16x8*>(
          &As[(wm * 64 + mt * 16 + row) * 106 + kk * 32 + kg * 8]);
#pragma unroll
    for (int nt = 0; nt < 3; ++nt)
      b[nt] = *reinterpret_cast<const bf16x8*>(
          &Ws[(wn * 48 + nt * 16 + row) * 106 + kk * 32 + kg * 8]);
#pragma unroll
    for (int mt = 0; mt < 4; ++mt)
#pragma unroll
      for (int nt = 0; nt < 3; ++nt)
        acc[mt][nt] = __builtin_amdgcn_mfma_f32_16x16x32_bf16(
            a[mt], b[nt], acc[mt][nt], 0, 0, 0);
  }
  __syncthreads();

#pragma unroll
  for (int nt = 0; nt < 3; ++nt) {
    int ocl = wn * 48 + nt * 16 + row;
    float bv = pb[ocl];
#pragma unroll
    for (int mt = 0; mt < 4; ++mt) {
      int pxl = wm * 64 + mt * 16 + kg * 4;
      f32x4 v = acc[mt][nt];
      float4 w = make_float4(v[0] + bv, v[1] + bv, v[2] + bv, v[3] + bv);
      *reinterpret_cast<float4*>(&tD[ocl * 132 + pxl]) = w;
    }
  }
  __syncthreads();
  float* ob = out + (size_t)(b0 + bz) * CC * HWC + p0;
#pragma unroll
  for (int r = 0; r < 12; ++r) {
    int lin = r * 256 + t;
    int o = lin >> 5, p4 = (lin & 31) * 4;
    float4 v = *reinterpret_cast<const float4*>(&tD[o * 132 + p4]);
    *reinterpret_cast<float4*>(ob + (size_t)o * HWC + p4) = v;
  }
}

extern "C" void kernel_launch(void* const* d_in, const int* in_sizes, int n_in,
                              void* d_out, int out_size, void* d_ws, size_t ws_size,
                              hipStream_t stream)
{
  const float* x      = (const float*)d_in[0];
  const float* qkv_w  = (const float*)d_in[1];
  const float* qkv_b  = (const float*)d_in[2];
  const float* dw_w   = (const float*)d_in[3];
  const float* dw_b   = (const float*)d_in[4];
  const float* proj_w = (const float*)d_in[5];
  const float* proj_b = (const float*)d_in[6];
  const float* temp   = (const float*)d_in[7];
  float* out = (float*)d_out;

  const size_t per_pre  = (size_t)C3 * HWC * 2;
  const size_t per_gp   = (size_t)NHEADS * CC * 1024 * 4;
  const size_t per_ssq  = (size_t)2 * 256 * 4;
  const size_t per_attn = (size_t)NHEADS * 1024 * 4;
  const size_t per_g    = (size_t)NHEADS * 1024 * 4;
  const size_t per_b = per_pre * 2 + per_gp + per_ssq + per_attn + per_g;

  int bc = 4;
  while (bc > 1 && per_b * (size_t)bc > ws_size) bc >>= 1;

  char* p = (char*)d_ws;
  unsigned short* pre = (unsigned short*)p; p += per_pre * bc;
  unsigned short* dwo = (unsigned short*)p; p += per_pre * bc;
  float* gpart = (float*)p; p += per_gp * bc;
  float* ssq   = (float*)p; p += per_ssq * bc;
  float* attn  = (float*)p; p += per_attn * bc;
  float* g     = (float*)p; p += per_g * bc;
  unsigned short* tbuf = pre;

  for (int b0 = 0; b0 < 4; b0 += bc) {
    k1_qkv_mfma<<<dim3(128, 3, bc), 256, 0, stream>>>(x, qkv_w, qkv_b, pre, b0);
    k2_dw<<<dim3(C3, 8, bc), 256, 0, stream>>>(pre, dw_w, dw_b, dwo);
    hipMemsetAsync(ssq, 0, per_ssq * bc, stream);
    k3_gram<<<dim3(CC, NHEADS, bc), 256, 0, stream>>>(dwo, gpart, ssq);
    k4a_reduce<<<dim3(NHEADS, 8, bc), 256, 0, stream>>>(gpart, g);
    k4b_softmax<<<dim3(NHEADS, bc), 64, 0, stream>>>(g, ssq, temp, attn);
    k5a_attnv<<<dim3(384, bc), 256, 0, stream>>>(dwo, attn, tbuf);
    k5b_proj<<<dim3(512, bc), 256, 0, stream>>>(tbuf, proj_w, proj_b, out, b0);
  }
}